// Round 6
// baseline (1215.992 us; speedup 1.0000x reference)
//
#include <hip/hip_runtime.h>

typedef float f32x4 __attribute__((ext_vector_type(4)));
typedef short bf16x8 __attribute__((ext_vector_type(8)));
typedef unsigned short u16x8 __attribute__((ext_vector_type(8)));
typedef unsigned short u16x4 __attribute__((ext_vector_type(4)));

#define KD 2048

static __device__ __forceinline__ unsigned short f2bf(float f) {
    __bf16 b = (__bf16)f;               // RNE
    return __builtin_bit_cast(unsigned short, b);
}
static __device__ __forceinline__ float bf2f(unsigned short h) {
    unsigned int u = ((unsigned int)h) << 16;
    return __builtin_bit_cast(float, u);
}
// async global->LDS, 16B per lane (dest = wave-uniform base + lane*16 linear;
// swizzles are applied on the GLOBAL source side)
static __device__ __forceinline__ void gl16(const unsigned short* g, unsigned short* l) {
    __builtin_amdgcn_global_load_lds(
        (const __attribute__((address_space(1))) unsigned int*)g,
        (__attribute__((address_space(3))) unsigned int*)l, 16, 0, 0);
}

// ---------------- RoPE tables ----------------
__global__ void rope_tables(float* __restrict__ cosT, float* __restrict__ sinT) {
    int i = blockIdx.x * 256 + threadIdx.x;          // 2048*64 entries
    if (i >= 2048 * 64) return;
    int s = i >> 6, j = i & 63;
    float freq = exp2f(-(2.0f * (float)j / 128.0f) * 13.287712379549449f);
    float a = (float)s * freq;
    cosT[i] = cosf(a);
    sinT[i] = sinf(a);
}

// ---------------- fp32 -> bf16 hi(/lo) split ----------------
__global__ void presplit(const float* __restrict__ src, unsigned short* __restrict__ dh,
                         unsigned short* __restrict__ dl, int n4) {
    int i = blockIdx.x * 256 + threadIdx.x;
    if (i >= n4) return;
    f32x4 v = ((const f32x4*)src)[i];
    u16x4 h, l;
#pragma unroll
    for (int j = 0; j < 4; ++j) {
        unsigned short hh = f2bf(v[j]);
        h[j] = hh;
        l[j] = f2bf(v[j] - bf2f(hh));
    }
    ((u16x4*)dh)[i] = h;
    if (dl) ((u16x4*)dl)[i] = l;
}

// ---------------- GEMM v2: D[i][j] = sum_k A[i][k]*B[j][k] ----------------
// MODE 0: Q (A=Wq fp32 reg-split 3-term, B=xh/xl gload) -> RoPE+scale, Qh bf16
// MODE 1: K (A=Wk)                                      -> RoPE, Kh bf16
// MODE 2: V (A=xh gload, B=Wvh gload, 1-term)           -> Vt bf16 (B,H,dh,S)
// MODE 3: O (A=Wo fp32 reg hi, B=attn_b bf16, 1-term)   -> fp32 (B,S,D)
template<int MODE>
__global__ __launch_bounds__(256)
void gemm2(const float* __restrict__ Af, const unsigned short* __restrict__ Abf,
           const unsigned short* __restrict__ Bh_g, const unsigned short* __restrict__ Bl_g,
           void* __restrict__ OutH,
           const float* __restrict__ cosT, const float* __restrict__ sinT)
{
    constexpr bool SPLIT = (MODE <= 1);      // 3-term
    constexpr bool A_REG = (MODE != 2);      // A staged from fp32 via regs
    constexpr int  ASTR  = A_REG ? 40 : 32;  // reg-path tiles padded, gload linear

    const int bi = blockIdx.x, bj = blockIdx.y;
    const int tid = threadIdx.x;
    const int lane = tid & 63;
    const int w = tid >> 6;
    const int wm = w >> 1, wn = w & 1;
    const int lg = lane >> 4, lr = lane & 15;

    __shared__ unsigned short As_h[128 * ASTR];
    __shared__ unsigned short As_l[SPLIT ? 128 * 40 : 8];
    __shared__ unsigned short Bs_h[128 * 32];
    __shared__ unsigned short Bs_l[SPLIT ? 128 * 32 : 8];

    const int ra = tid >> 1;                  // 0..127
    const int ka = (tid & 1) * 16;            // 0 or 16
    const float* Ag = A_REG ? (Af + (size_t)(bi * 128 + ra) * KD + ka) : nullptr;

    f32x4 acc[4][4];
#pragma unroll
    for (int i = 0; i < 4; ++i)
#pragma unroll
        for (int j = 0; j < 4; ++j) acc[i][j] = f32x4{0.f, 0.f, 0.f, 0.f};

    f32x4 avA[4];
    auto loadA = [&](int k0) {
        if constexpr (A_REG) {
#pragma unroll
            for (int i = 0; i < 4; ++i) avA[i] = *(const f32x4*)(Ag + k0 + i * 4);
        }
    };
    auto writeA = [&]() {
        if constexpr (A_REG) {
            u16x8 h0, h1;
            if constexpr (SPLIT) {
                u16x8 l0, l1;
#pragma unroll
                for (int i = 0; i < 4; ++i) {
                    unsigned short h;
                    h = f2bf(avA[0][i]); h0[i]     = h; l0[i]     = f2bf(avA[0][i] - bf2f(h));
                    h = f2bf(avA[1][i]); h0[4 + i] = h; l0[4 + i] = f2bf(avA[1][i] - bf2f(h));
                    h = f2bf(avA[2][i]); h1[i]     = h; l1[i]     = f2bf(avA[2][i] - bf2f(h));
                    h = f2bf(avA[3][i]); h1[4 + i] = h; l1[4 + i] = f2bf(avA[3][i] - bf2f(h));
                }
                *(u16x8*)&As_l[ra * 40 + ka]     = l0;
                *(u16x8*)&As_l[ra * 40 + ka + 8] = l1;
            } else {
#pragma unroll
                for (int i = 0; i < 4; ++i) {
                    h0[i]     = f2bf(avA[0][i]);
                    h0[4 + i] = f2bf(avA[1][i]);
                    h1[i]     = f2bf(avA[2][i]);
                    h1[4 + i] = f2bf(avA[3][i]);
                }
            }
            *(u16x8*)&As_h[ra * 40 + ka]     = h0;
            *(u16x8*)&As_h[ra * 40 + ka + 8] = h1;
        }
    };
    auto stageB = [&](int k0) {
#pragma unroll
        for (int q2 = 0; q2 < 2; ++q2) {
            const int seg = w * 2 + q2;                 // 0..7
            const int row = seg * 16 + (lane >> 2);     // 0..127
            const int loff = seg * 512 + lane * 8;      // shorts
            const size_t gs = (size_t)(bj * 128 + row) * KD + k0 + (lane & 3) * 8;
            gl16(Bh_g + gs, &Bs_h[loff]);
            if constexpr (SPLIT) gl16(Bl_g + gs, &Bs_l[loff]);
            if constexpr (!A_REG) {
                const size_t ga = (size_t)(bi * 128 + row) * KD + k0 + (lane & 3) * 8;
                gl16(Abf + ga, &As_h[loff]);
            }
        }
    };
    auto term = [&](const unsigned short* As_, const unsigned short* Bs_) {
        const unsigned short* Ap = &As_[(wm * 64 + lr) * ASTR + lg * 8];
        const unsigned short* Bp = &Bs_[(wn * 64 + lr) * 32 + lg * 8];
        bf16x8 af[4], bf[4];
#pragma unroll
        for (int i = 0; i < 4; ++i) {
            af[i] = *(const bf16x8*)(Ap + i * 16 * ASTR);
            bf[i] = *(const bf16x8*)(Bp + i * 16 * 32);
        }
#pragma unroll
        for (int mi = 0; mi < 4; ++mi)
#pragma unroll
            for (int ni = 0; ni < 4; ++ni)
                acc[mi][ni] = __builtin_amdgcn_mfma_f32_16x16x32_bf16(af[mi], bf[ni], acc[mi][ni], 0, 0, 0);
    };

    loadA(0);
#pragma unroll 1
    for (int kt = 0; kt < 64; ++kt) {
        const int k0 = kt * 32;
        __syncthreads();                 // previous compute done; LDS reusable
        writeA();
        stageB(k0);
        if (kt < 63) loadA(k0 + 32);     // prefetch next A (overlaps compute)
        __syncthreads();                 // staging visible (vmcnt+lgkm drained)
        term(As_h, Bs_h);
        if constexpr (SPLIT) {
            const unsigned short* Ap = &As_l[0];
            term(As_h, Bs_l);
            term(Ap,   Bs_h);
        }
    }

    if constexpr (MODE <= 1) {
        unsigned short* OH = (unsigned short*)OutH;
        const float scale = (MODE == 0) ? 0.08838834764831845f : 1.0f;
#pragma unroll
        for (int mi = 0; mi < 4; ++mi) {
            int i0 = bi * 128 + wm * 64 + mi * 16 + lg * 4;  // dout, 4 consecutive
            int h = i0 >> 7, dd = i0 & 127;
            int jp = dd >> 1;
#pragma unroll
            for (int ni = 0; ni < 4; ++ni) {
                int jj = bj * 128 + wn * 64 + ni * 16 + lr;  // token
                int b = jj >> 11, s = jj & 2047;
                float c0 = cosT[s * 64 + jp],     s0 = sinT[s * 64 + jp];
                float c1 = cosT[s * 64 + jp + 1], s1 = sinT[s * 64 + jp + 1];
                f32x4 v = acc[mi][ni];
                float r0 = (v[0] * c0 - v[1] * s0) * scale;
                float r1 = (v[0] * s0 + v[1] * c0) * scale;
                float r2 = (v[2] * c1 - v[3] * s1) * scale;
                float r3 = (v[2] * s1 + v[3] * c1) * scale;
                u16x4 ph = { f2bf(r0), f2bf(r1), f2bf(r2), f2bf(r3) };
                *(u16x4*)&OH[((size_t)(b * 16 + h) * 2048 + s) * 128 + dd] = ph;
            }
        }
    } else if constexpr (MODE == 2) {
        unsigned short* O = (unsigned short*)OutH;
#pragma unroll
        for (int mi = 0; mi < 4; ++mi) {
            int i0 = bi * 128 + wm * 64 + mi * 16 + lg * 4;  // token, 4 consecutive
            int b = i0 >> 11, s = i0 & 2047;
#pragma unroll
            for (int ni = 0; ni < 4; ++ni) {
                int jj = bj * 128 + wn * 64 + ni * 16 + lr;  // dout
                int h = jj >> 7, dd = jj & 127;
                f32x4 v = acc[mi][ni];
                u16x4 pk = { f2bf(v[0]), f2bf(v[1]), f2bf(v[2]), f2bf(v[3]) };
                *(u16x4*)&O[((size_t)(b * 16 + h) * 128 + dd) * 2048 + s] = pk;
            }
        }
    } else {
        float* O = (float*)OutH;
#pragma unroll
        for (int mi = 0; mi < 4; ++mi) {
            int i0 = bi * 128 + wm * 64 + mi * 16 + lg * 4;  // dout, 4 consecutive
#pragma unroll
            for (int ni = 0; ni < 4; ++ni) {
                int jj = bj * 128 + wn * 64 + ni * 16 + lr;  // token
                *(f32x4*)&O[(size_t)jj * 2048 + i0] = acc[mi][ni];
            }
        }
    }
}

// ---------------- causal flash attention v3 ----------------
// 512 blocks = 64 bh x 8 pair-slots; block p does qt=15-p then qt=p (68 iters
// const -> balanced). 4 waves x 32 q-rows. 1-term QK^T (kh*qh). LDS 37.4KB ->
// 4 blocks/CU. K swizzle ^(row&7), V swizzle ^((row>>1)&3), Ps stride 40:
// all conflict-free at quarter-wave granularity. T13 defer-max THR=8.
__global__ __launch_bounds__(256, 4)
void attn3(const unsigned short* __restrict__ Qh, const unsigned short* __restrict__ Kh,
           const unsigned short* __restrict__ Vt, unsigned short* __restrict__ Ob)
{
    const int bid = blockIdx.x;
    const int bh = bid & 63;
    const int p  = bid >> 6;                 // 0..7
    const int tid = threadIdx.x;
    const int lane = tid & 63, w = tid >> 6;
    const int lg = lane >> 4, lr = lane & 15;
    const int b = bh >> 4, h = bh & 15;

    __shared__ unsigned short Ks[2][32 * 128];   // 8KB x2, swizzled ^(row&7)
    __shared__ unsigned short Vs[2][128 * 32];   // 8KB x2, swizzled ^((row>>1)&3)
    __shared__ unsigned short Ps[4][16 * 40];    // 5KB, padded stride 40

    auto stage = [&](int t) {
        const int buf = t & 1;
        const int kv0 = t * 32;
#pragma unroll
        for (int q2 = 0; q2 < 2; ++q2) {
            const int seg = w * 2 + q2;                      // 0..7
            {   // K: 256B rows, chunk ^ (row&7)
                const int row = seg * 4 + (lane >> 4);
                const int gcol = 8 * ((lane & 15) ^ (row & 7));
                gl16(Kh + ((size_t)bh * 2048 + kv0 + row) * 128 + gcol,
                     &Ks[buf][seg * 512 + lane * 8]);
            }
            {   // V: 64B rows, chunk ^ ((row>>1)&3)
                const int row = seg * 16 + (lane >> 2);      // d 0..127
                const int gcol = 8 * ((lane & 3) ^ ((row >> 1) & 3));
                gl16(Vt + ((size_t)bh * 128 + row) * 2048 + kv0 + gcol,
                     &Vs[buf][seg * 512 + lane * 8]);
            }
        }
    };

#pragma unroll 1
    for (int half = 0; half < 2; ++half) {
        const int qt = half ? p : (15 - p);
        const int qbase = qt * 128 + w * 32;
        const int qmaxw = qbase + 31;
        const int nkv = 4 * (qt + 1);

        bf16x8 qf[2][4];
#pragma unroll
        for (int qg = 0; qg < 2; ++qg) {
            const size_t qoff = ((size_t)bh * 2048 + qbase + qg * 16 + lr) * 128;
#pragma unroll
            for (int kk = 0; kk < 4; ++kk)
                qf[qg][kk] = *(const bf16x8*)(Qh + qoff + kk * 32 + lg * 8);
        }

        f32x4 o[8][2];
#pragma unroll
        for (int i = 0; i < 8; ++i)
#pragma unroll
            for (int qg = 0; qg < 2; ++qg) o[i][qg] = f32x4{0.f, 0.f, 0.f, 0.f};
        float m_run[2] = { -1e30f, -1e30f }, l_run[2] = { 0.f, 0.f };

        stage(0);
        __syncthreads();

#pragma unroll 1
        for (int t = 0; t < nkv; ++t) {
            if (t + 1 < nkv) stage(t + 1);       // issue-early into other buffer
            const int buf = t & 1;
            const int kv0 = t * 32;
            if (kv0 <= qmaxw) {
                // QK^T swapped, 1-term: D[kv][q], lane: q=lr, kv=m2*16+lg*4+rr
                f32x4 sc[2][2];
#pragma unroll
                for (int m2 = 0; m2 < 2; ++m2)
#pragma unroll
                    for (int qg = 0; qg < 2; ++qg) sc[m2][qg] = f32x4{0.f, 0.f, 0.f, 0.f};
#pragma unroll
                for (int m2 = 0; m2 < 2; ++m2)
#pragma unroll
                    for (int kk = 0; kk < 4; ++kk) {
                        const int go = 8 * ((4 * kk + lg) ^ (lr & 7));
                        bf16x8 kf = *(const bf16x8*)&Ks[buf][(m2 * 16 + lr) * 128 + go];
#pragma unroll
                        for (int qg = 0; qg < 2; ++qg)
                            sc[m2][qg] = __builtin_amdgcn_mfma_f32_16x16x32_bf16(kf, qf[qg][kk], sc[m2][qg], 0, 0, 0);
                    }
#pragma unroll
                for (int qg = 0; qg < 2; ++qg) {
                    const int q = qbase + qg * 16 + lr;
                    float pmax = -1e30f;
#pragma unroll
                    for (int m2 = 0; m2 < 2; ++m2)
#pragma unroll
                        for (int rr = 0; rr < 4; ++rr) {
                            int kvg = kv0 + m2 * 16 + lg * 4 + rr;
                            float sv = (kvg <= q) ? sc[m2][qg][rr] : -1e30f;
                            sc[m2][qg][rr] = sv;
                            pmax = fmaxf(pmax, sv);
                        }
                    pmax = fmaxf(pmax, __shfl_xor(pmax, 16));
                    pmax = fmaxf(pmax, __shfl_xor(pmax, 32));
                    // T13 defer-max: skip rescale unless max grew past THR=8
                    if (!__all(pmax <= m_run[qg] + 8.0f)) {
                        float mnew = fmaxf(m_run[qg], pmax);
                        float alpha = __expf(m_run[qg] - mnew);
                        m_run[qg] = mnew;
                        l_run[qg] *= alpha;
#pragma unroll
                        for (int ni = 0; ni < 8; ++ni) {
                            o[ni][qg][0] *= alpha; o[ni][qg][1] *= alpha;
                            o[ni][qg][2] *= alpha; o[ni][qg][3] *= alpha;
                        }
                    }
                    float psum = 0.f;
                    u16x4 pq[2];
#pragma unroll
                    for (int m2 = 0; m2 < 2; ++m2)
#pragma unroll
                        for (int rr = 0; rr < 4; ++rr) {
                            float pv = __expf(sc[m2][qg][rr] - m_run[qg]);
                            unsigned short ph = f2bf(pv);
                            pq[m2][rr] = ph;
                            psum += bf2f(ph);    // consistent with PV numerator
                        }
                    l_run[qg] += psum;
                    // P relay: C-layout -> B-frag via per-wave LDS (stride 40)
                    *(u16x4*)&Ps[w][lr * 40 + lg * 4]      = pq[0];
                    *(u16x4*)&Ps[w][lr * 40 + 16 + lg * 4] = pq[1];
                    bf16x8 pf = *(const bf16x8*)&Ps[w][lr * 40 + lg * 8];
                    // PV swapped: O^T[d][q], A = Vt rows (d), B = P (K=32)
#pragma unroll
                    for (int ni = 0; ni < 8; ++ni) {
                        bf16x8 vf = *(const bf16x8*)&Vs[buf][(ni * 16 + lr) * 32 + 8 * (lg ^ ((lr >> 1) & 3))];
                        o[ni][qg] = __builtin_amdgcn_mfma_f32_16x16x32_bf16(vf, pf, o[ni][qg], 0, 0, 0);
                    }
                }
            }
            __syncthreads();
        }

#pragma unroll
        for (int qg = 0; qg < 2; ++qg) {
            float l = l_run[qg];
            l += __shfl_xor(l, 16);
            l += __shfl_xor(l, 32);
            float inv = 1.f / l;
            const int q = qbase + qg * 16 + lr;
            unsigned short* Op = Ob + (((size_t)(b * 2048 + q) * 16 + h) * 128);
#pragma unroll
            for (int ni = 0; ni < 8; ++ni) {
                u16x4 pk = { f2bf(o[ni][qg][0] * inv), f2bf(o[ni][qg][1] * inv),
                             f2bf(o[ni][qg][2] * inv), f2bf(o[ni][qg][3] * inv) };
                *(u16x4*)&Op[ni * 16 + lg * 4] = pk;
            }
        }
    }
}

extern "C" void kernel_launch(void* const* d_in, const int* in_sizes, int n_in,
                              void* d_out, int out_size, void* d_ws, size_t ws_size,
                              hipStream_t stream) {
    const float* x  = (const float*)d_in[0];
    const float* Wq = (const float*)d_in[1];
    const float* Wk = (const float*)d_in[2];
    const float* Wv = (const float*)d_in[3];
    const float* Wo = (const float*)d_in[4];

    char* ws = (char*)d_ws;
    float* cosT = (float*)ws;                                   // 512 KB
    float* sinT = cosT + 2048 * 64;                             // 512 KB
    unsigned short* xh  = (unsigned short*)(ws + (1 << 20));    // 32 MB
    unsigned short* xl  = xh  + (size_t)16777216;               // 32 MB
    unsigned short* Wvh = xl  + (size_t)16777216;               // 8 MB (ws ~73 MB)

    // aliases (lifetimes disjoint): Vt overwrites xl after Q/K GEMMs;
    // attn_b overwrites xh after V GEMM.
    unsigned short* Vt     = xl;
    unsigned short* attn_b = xh;

    // d_out (67 MB fp32) hosts Qh/Kh until the final GEMM overwrites it
    unsigned short* Qh = (unsigned short*)d_out;
    unsigned short* Kh = Qh + (size_t)16777216;

    rope_tables<<<dim3(512), 256, 0, stream>>>(cosT, sinT);
    presplit<<<dim3(16384), 256, 0, stream>>>(x, xh, xl, 4194304);
    presplit<<<dim3(4096), 256, 0, stream>>>(Wv, Wvh, nullptr, 1048576);

    gemm2<0><<<dim3(16, 64), 256, 0, stream>>>(Wq, nullptr, xh, xl, Qh, cosT, sinT);
    gemm2<1><<<dim3(16, 64), 256, 0, stream>>>(Wk, nullptr, xh, xl, Kh, cosT, sinT);
    gemm2<2><<<dim3(64, 16), 256, 0, stream>>>(nullptr, xh, Wvh, nullptr, Vt, cosT, sinT);
    attn3<<<dim3(512), 256, 0, stream>>>(Qh, Kh, Vt, attn_b);
    gemm2<3><<<dim3(16, 64), 256, 0, stream>>>(Wo, nullptr, attn_b, nullptr, d_out, cosT, sinT);
}

// Round 7
// 958.221 us; speedup vs baseline: 1.2690x; 1.2690x over previous
//
#include <hip/hip_runtime.h>

typedef float f32x4 __attribute__((ext_vector_type(4)));
typedef short bf16x8 __attribute__((ext_vector_type(8)));
typedef unsigned short u16x8 __attribute__((ext_vector_type(8)));
typedef unsigned short u16x4 __attribute__((ext_vector_type(4)));

#define KD 2048

static __device__ __forceinline__ unsigned short f2bf(float f) {
    __bf16 b = (__bf16)f;               // RNE
    return __builtin_bit_cast(unsigned short, b);
}
static __device__ __forceinline__ float bf2f(unsigned short h) {
    unsigned int u = ((unsigned int)h) << 16;
    return __builtin_bit_cast(float, u);
}
// async global->LDS, 16B per lane (dest = wave-uniform base + lane*16 linear;
// swizzles are applied on the GLOBAL source side)
static __device__ __forceinline__ void gl16(const unsigned short* g, unsigned short* l) {
    __builtin_amdgcn_global_load_lds(
        (const __attribute__((address_space(1))) unsigned int*)g,
        (__attribute__((address_space(3))) unsigned int*)l, 16, 0, 0);
}

// ---------------- RoPE tables ----------------
__global__ void rope_tables(float* __restrict__ cosT, float* __restrict__ sinT) {
    int i = blockIdx.x * 256 + threadIdx.x;          // 2048*64 entries
    if (i >= 2048 * 64) return;
    int s = i >> 6, j = i & 63;
    float freq = exp2f(-(2.0f * (float)j / 128.0f) * 13.287712379549449f);
    float a = (float)s * freq;
    cosT[i] = cosf(a);
    sinT[i] = sinf(a);
}

// ---------------- fp32 -> bf16 hi(/lo) split ----------------
__global__ void presplit(const float* __restrict__ src, unsigned short* __restrict__ dh,
                         unsigned short* __restrict__ dl, int n4) {
    int i = blockIdx.x * 256 + threadIdx.x;
    if (i >= n4) return;
    f32x4 v = ((const f32x4*)src)[i];
    u16x4 h, l;
#pragma unroll
    for (int j = 0; j < 4; ++j) {
        unsigned short hh = f2bf(v[j]);
        h[j] = hh;
        l[j] = f2bf(v[j] - bf2f(hh));
    }
    ((u16x4*)dh)[i] = h;
    if (dl) ((u16x4*)dl)[i] = l;
}

// ---------------- GEMM v2: D[i][j] = sum_k A[i][k]*B[j][k] ----------------
// MODE 0: Q (A=Wq fp32 reg-split 3-term, B=xh/xl gload) -> RoPE+scale, Qh bf16
// MODE 1: K (A=Wk)                                      -> RoPE, Kh bf16
// MODE 2: V (A=xh gload, B=Wvh gload, 1-term)           -> Vt bf16 (B,H,dh,S)
// MODE 3: O (A=Wo fp32 reg hi, B=attn_b bf16, 1-term)   -> fp32 (B,S,D)
template<int MODE>
__global__ __launch_bounds__(256)
void gemm2(const float* __restrict__ Af, const unsigned short* __restrict__ Abf,
           const unsigned short* __restrict__ Bh_g, const unsigned short* __restrict__ Bl_g,
           void* __restrict__ OutH,
           const float* __restrict__ cosT, const float* __restrict__ sinT)
{
    constexpr bool SPLIT = (MODE <= 1);      // 3-term
    constexpr bool A_REG = (MODE != 2);      // A staged from fp32 via regs
    constexpr int  ASTR  = A_REG ? 40 : 32;  // reg-path tiles padded, gload linear

    const int bi = blockIdx.x, bj = blockIdx.y;
    const int tid = threadIdx.x;
    const int lane = tid & 63;
    const int w = tid >> 6;
    const int wm = w >> 1, wn = w & 1;
    const int lg = lane >> 4, lr = lane & 15;

    __shared__ unsigned short As_h[128 * ASTR];
    __shared__ unsigned short As_l[SPLIT ? 128 * 40 : 8];
    __shared__ unsigned short Bs_h[128 * 32];
    __shared__ unsigned short Bs_l[SPLIT ? 128 * 32 : 8];

    const int ra = tid >> 1;                  // 0..127
    const int ka = (tid & 1) * 16;            // 0 or 16
    const float* Ag = A_REG ? (Af + (size_t)(bi * 128 + ra) * KD + ka) : nullptr;

    f32x4 acc[4][4];
#pragma unroll
    for (int i = 0; i < 4; ++i)
#pragma unroll
        for (int j = 0; j < 4; ++j) acc[i][j] = f32x4{0.f, 0.f, 0.f, 0.f};

    f32x4 avA[4];
    auto loadA = [&](int k0) {
        if constexpr (A_REG) {
#pragma unroll
            for (int i = 0; i < 4; ++i) avA[i] = *(const f32x4*)(Ag + k0 + i * 4);
        }
    };
    auto writeA = [&]() {
        if constexpr (A_REG) {
            u16x8 h0, h1;
            if constexpr (SPLIT) {
                u16x8 l0, l1;
#pragma unroll
                for (int i = 0; i < 4; ++i) {
                    unsigned short h;
                    h = f2bf(avA[0][i]); h0[i]     = h; l0[i]     = f2bf(avA[0][i] - bf2f(h));
                    h = f2bf(avA[1][i]); h0[4 + i] = h; l0[4 + i] = f2bf(avA[1][i] - bf2f(h));
                    h = f2bf(avA[2][i]); h1[i]     = h; l1[i]     = f2bf(avA[2][i] - bf2f(h));
                    h = f2bf(avA[3][i]); h1[4 + i] = h; l1[4 + i] = f2bf(avA[3][i] - bf2f(h));
                }
                *(u16x8*)&As_l[ra * 40 + ka]     = l0;
                *(u16x8*)&As_l[ra * 40 + ka + 8] = l1;
            } else {
#pragma unroll
                for (int i = 0; i < 4; ++i) {
                    h0[i]     = f2bf(avA[0][i]);
                    h0[4 + i] = f2bf(avA[1][i]);
                    h1[i]     = f2bf(avA[2][i]);
                    h1[4 + i] = f2bf(avA[3][i]);
                }
            }
            *(u16x8*)&As_h[ra * 40 + ka]     = h0;
            *(u16x8*)&As_h[ra * 40 + ka + 8] = h1;
        }
    };
    auto stageB = [&](int k0) {
#pragma unroll
        for (int q2 = 0; q2 < 2; ++q2) {
            const int seg = w * 2 + q2;                 // 0..7
            const int row = seg * 16 + (lane >> 2);     // 0..127
            const int loff = seg * 512 + lane * 8;      // shorts
            const size_t gs = (size_t)(bj * 128 + row) * KD + k0 + (lane & 3) * 8;
            gl16(Bh_g + gs, &Bs_h[loff]);
            if constexpr (SPLIT) gl16(Bl_g + gs, &Bs_l[loff]);
            if constexpr (!A_REG) {
                const size_t ga = (size_t)(bi * 128 + row) * KD + k0 + (lane & 3) * 8;
                gl16(Abf + ga, &As_h[loff]);
            }
        }
    };
    auto term = [&](const unsigned short* As_, const unsigned short* Bs_) {
        const unsigned short* Ap = &As_[(wm * 64 + lr) * ASTR + lg * 8];
        const unsigned short* Bp = &Bs_[(wn * 64 + lr) * 32 + lg * 8];
        bf16x8 af[4], bf[4];
#pragma unroll
        for (int i = 0; i < 4; ++i) {
            af[i] = *(const bf16x8*)(Ap + i * 16 * ASTR);
            bf[i] = *(const bf16x8*)(Bp + i * 16 * 32);
        }
#pragma unroll
        for (int mi = 0; mi < 4; ++mi)
#pragma unroll
            for (int ni = 0; ni < 4; ++ni)
                acc[mi][ni] = __builtin_amdgcn_mfma_f32_16x16x32_bf16(af[mi], bf[ni], acc[mi][ni], 0, 0, 0);
    };

    loadA(0);
#pragma unroll 1
    for (int kt = 0; kt < 64; ++kt) {
        const int k0 = kt * 32;
        __syncthreads();                 // previous compute done; LDS reusable
        writeA();
        stageB(k0);
        if (kt < 63) loadA(k0 + 32);     // prefetch next A (overlaps compute)
        __syncthreads();                 // staging visible (vmcnt+lgkm drained)
        term(As_h, Bs_h);
        if constexpr (SPLIT) {
            const unsigned short* Ap = &As_l[0];
            term(As_h, Bs_l);
            term(Ap,   Bs_h);
        }
    }

    if constexpr (MODE <= 1) {
        unsigned short* OH = (unsigned short*)OutH;
        const float scale = (MODE == 0) ? 0.08838834764831845f : 1.0f;
#pragma unroll
        for (int mi = 0; mi < 4; ++mi) {
            int i0 = bi * 128 + wm * 64 + mi * 16 + lg * 4;  // dout, 4 consecutive
            int h = i0 >> 7, dd = i0 & 127;
            int jp = dd >> 1;
#pragma unroll
            for (int ni = 0; ni < 4; ++ni) {
                int jj = bj * 128 + wn * 64 + ni * 16 + lr;  // token
                int b = jj >> 11, s = jj & 2047;
                float c0 = cosT[s * 64 + jp],     s0 = sinT[s * 64 + jp];
                float c1 = cosT[s * 64 + jp + 1], s1 = sinT[s * 64 + jp + 1];
                f32x4 v = acc[mi][ni];
                float r0 = (v[0] * c0 - v[1] * s0) * scale;
                float r1 = (v[0] * s0 + v[1] * c0) * scale;
                float r2 = (v[2] * c1 - v[3] * s1) * scale;
                float r3 = (v[2] * s1 + v[3] * c1) * scale;
                u16x4 ph = { f2bf(r0), f2bf(r1), f2bf(r2), f2bf(r3) };
                *(u16x4*)&OH[((size_t)(b * 16 + h) * 2048 + s) * 128 + dd] = ph;
            }
        }
    } else if constexpr (MODE == 2) {
        unsigned short* O = (unsigned short*)OutH;
#pragma unroll
        for (int mi = 0; mi < 4; ++mi) {
            int i0 = bi * 128 + wm * 64 + mi * 16 + lg * 4;  // token, 4 consecutive
            int b = i0 >> 11, s = i0 & 2047;
#pragma unroll
            for (int ni = 0; ni < 4; ++ni) {
                int jj = bj * 128 + wn * 64 + ni * 16 + lr;  // dout
                int h = jj >> 7, dd = jj & 127;
                f32x4 v = acc[mi][ni];
                u16x4 pk = { f2bf(v[0]), f2bf(v[1]), f2bf(v[2]), f2bf(v[3]) };
                *(u16x4*)&O[((size_t)(b * 16 + h) * 128 + dd) * 2048 + s] = pk;
            }
        }
    } else {
        float* O = (float*)OutH;
#pragma unroll
        for (int mi = 0; mi < 4; ++mi) {
            int i0 = bi * 128 + wm * 64 + mi * 16 + lg * 4;  // dout, 4 consecutive
#pragma unroll
            for (int ni = 0; ni < 4; ++ni) {
                int jj = bj * 128 + wn * 64 + ni * 16 + lr;  // token
                *(f32x4*)&O[(size_t)jj * 2048 + i0] = acc[mi][ni];
            }
        }
    }
}

// ---------------- causal flash attention v4 (wave-pair split) ----------------
// 1024 blocks = 64 bh x 16 pair-slots; block p does qt=31-p then qt=p over
// 64-row q-tiles -> exactly 66 iters/block, 1024 = 256CU x 4 blocks: one
// perfectly balanced wave of blocks. Block = 2 pairs x 2 waves: pair owns
// 32 q-rows; both waves duplicate QK^T+softmax (identical, deterministic),
// split PV across d-halves -> per-wave state ~100 VGPR, fits (256,4) cap 128.
// K swizzle ^(row&7), V swizzle ^((row>>1)&3), Ps stride 40. T13 defer-max.
__global__ __launch_bounds__(256, 4)
void attn4(const unsigned short* __restrict__ Qh, const unsigned short* __restrict__ Kh,
           const unsigned short* __restrict__ Vt, unsigned short* __restrict__ Ob)
{
    const int bid = blockIdx.x;
    const int bh = bid & 63;
    const int p  = bid >> 6;                 // 0..15
    const int tid = threadIdx.x;
    const int lane = tid & 63, w = tid >> 6;
    const int pair = w >> 1, dhalf = w & 1;
    const int lg = lane >> 4, lr = lane & 15;
    const int b = bh >> 4, h = bh & 15;

    __shared__ unsigned short Ks[2][32 * 128];   // 8KB x2, swizzled ^(row&7)
    __shared__ unsigned short Vs[2][128 * 32];   // 8KB x2, swizzled ^((row>>1)&3)
    __shared__ unsigned short Ps[2][2][16 * 40]; // [pair][qg], stride 40

    auto stage = [&](int t) {
        const int buf = t & 1;
        const int kv0 = t * 32;
#pragma unroll
        for (int q2 = 0; q2 < 2; ++q2) {
            const int seg = w * 2 + q2;                      // 0..7
            {   // K: 256B rows, chunk ^ (row&7)
                const int row = seg * 4 + (lane >> 4);
                const int gcol = 8 * ((lane & 15) ^ (row & 7));
                gl16(Kh + ((size_t)bh * 2048 + kv0 + row) * 128 + gcol,
                     &Ks[buf][seg * 512 + lane * 8]);
            }
            {   // V: 64B rows, chunk ^ ((row>>1)&3)
                const int row = seg * 16 + (lane >> 2);      // d 0..127
                const int gcol = 8 * ((lane & 3) ^ ((row >> 1) & 3));
                gl16(Vt + ((size_t)bh * 128 + row) * 2048 + kv0 + gcol,
                     &Vs[buf][seg * 512 + lane * 8]);
            }
        }
    };

#pragma unroll 1
    for (int half = 0; half < 2; ++half) {
        const int qt = half ? p : (31 - p);          // 64-row q-tile index
        const int qbase = qt * 64 + pair * 32;
        const int qmaxw = qbase + 31;
        const int nkv = 2 * (qt + 1);

        bf16x8 qf[2][4];
#pragma unroll
        for (int qg = 0; qg < 2; ++qg) {
            const size_t qoff = ((size_t)bh * 2048 + qbase + qg * 16 + lr) * 128;
#pragma unroll
            for (int kk = 0; kk < 4; ++kk)
                qf[qg][kk] = *(const bf16x8*)(Qh + qoff + kk * 32 + lg * 8);
        }

        f32x4 o[4][2];
#pragma unroll
        for (int i = 0; i < 4; ++i)
#pragma unroll
            for (int qg = 0; qg < 2; ++qg) o[i][qg] = f32x4{0.f, 0.f, 0.f, 0.f};
        float m_run[2] = { -1e30f, -1e30f }, l_run[2] = { 0.f, 0.f };

        stage(0);
        __syncthreads();

#pragma unroll 1
        for (int t = 0; t < nkv; ++t) {
            if (t + 1 < nkv) stage(t + 1);       // issue-early into other buffer
            const int buf = t & 1;
            const int kv0 = t * 32;
            if (kv0 <= qmaxw) {
                // QK^T swapped, 1-term: D[kv][q]; lane: q=lr, kv=m2*16+lg*4+rr
                f32x4 sc[2][2];
#pragma unroll
                for (int m2 = 0; m2 < 2; ++m2)
#pragma unroll
                    for (int qg = 0; qg < 2; ++qg) sc[m2][qg] = f32x4{0.f, 0.f, 0.f, 0.f};
#pragma unroll
                for (int m2 = 0; m2 < 2; ++m2)
#pragma unroll
                    for (int kk = 0; kk < 4; ++kk) {
                        const int go = 8 * ((4 * kk + lg) ^ (lr & 7));
                        bf16x8 kf = *(const bf16x8*)&Ks[buf][(m2 * 16 + lr) * 128 + go];
#pragma unroll
                        for (int qg = 0; qg < 2; ++qg)
                            sc[m2][qg] = __builtin_amdgcn_mfma_f32_16x16x32_bf16(kf, qf[qg][kk], sc[m2][qg], 0, 0, 0);
                    }
#pragma unroll
                for (int qg = 0; qg < 2; ++qg) {
                    const int q = qbase + qg * 16 + lr;
                    float pmax = -1e30f;
#pragma unroll
                    for (int m2 = 0; m2 < 2; ++m2)
#pragma unroll
                        for (int rr = 0; rr < 4; ++rr) {
                            int kvg = kv0 + m2 * 16 + lg * 4 + rr;
                            float sv = (kvg <= q) ? sc[m2][qg][rr] : -1e30f;
                            sc[m2][qg][rr] = sv;
                            pmax = fmaxf(pmax, sv);
                        }
                    pmax = fmaxf(pmax, __shfl_xor(pmax, 16));
                    pmax = fmaxf(pmax, __shfl_xor(pmax, 32));
                    // T13 defer-max: skip rescale unless max grew past THR=8
                    if (!__all(pmax <= m_run[qg] + 8.0f)) {
                        float mnew = fmaxf(m_run[qg], pmax);
                        float alpha = __expf(m_run[qg] - mnew);
                        m_run[qg] = mnew;
                        l_run[qg] *= alpha;
#pragma unroll
                        for (int ni = 0; ni < 4; ++ni) {
                            o[ni][qg][0] *= alpha; o[ni][qg][1] *= alpha;
                            o[ni][qg][2] *= alpha; o[ni][qg][3] *= alpha;
                        }
                    }
                    float psum = 0.f;
                    u16x4 pq[2];
#pragma unroll
                    for (int m2 = 0; m2 < 2; ++m2)
#pragma unroll
                        for (int rr = 0; rr < 4; ++rr) {
                            float pv = __expf(sc[m2][qg][rr] - m_run[qg]);
                            unsigned short ph = f2bf(pv);
                            pq[m2][rr] = ph;
                            psum += bf2f(ph);    // consistent with PV numerator
                        }
                    l_run[qg] += psum;
                    // P relay: C-layout -> B-frag; both pair-waves write
                    // identical values (benign); stride 40 = conflict-free
                    *(u16x4*)&Ps[pair][qg][lr * 40 + lg * 4]      = pq[0];
                    *(u16x4*)&Ps[pair][qg][lr * 40 + 16 + lg * 4] = pq[1];
                    bf16x8 pf = *(const bf16x8*)&Ps[pair][qg][lr * 40 + lg * 8];
                    // PV swapped: O^T[d][q]; this wave covers its d-half
#pragma unroll
                    for (int ni = 0; ni < 4; ++ni) {
                        const int dr = (dhalf * 4 + ni) * 16 + lr;
                        bf16x8 vf = *(const bf16x8*)&Vs[buf][dr * 32 + 8 * (lg ^ ((lr >> 1) & 3))];
                        o[ni][qg] = __builtin_amdgcn_mfma_f32_16x16x32_bf16(vf, pf, o[ni][qg], 0, 0, 0);
                    }
                }
            }
            __syncthreads();
        }

#pragma unroll
        for (int qg = 0; qg < 2; ++qg) {
            float l = l_run[qg];
            l += __shfl_xor(l, 16);
            l += __shfl_xor(l, 32);
            float inv = 1.f / l;
            const int q = qbase + qg * 16 + lr;
            unsigned short* Op = Ob + (((size_t)(b * 2048 + q) * 16 + h) * 128) + dhalf * 64;
#pragma unroll
            for (int ni = 0; ni < 4; ++ni) {
                u16x4 pk = { f2bf(o[ni][qg][0] * inv), f2bf(o[ni][qg][1] * inv),
                             f2bf(o[ni][qg][2] * inv), f2bf(o[ni][qg][3] * inv) };
                *(u16x4*)&Op[ni * 16 + lg * 4] = pk;
            }
        }
    }
}

extern "C" void kernel_launch(void* const* d_in, const int* in_sizes, int n_in,
                              void* d_out, int out_size, void* d_ws, size_t ws_size,
                              hipStream_t stream) {
    const float* x  = (const float*)d_in[0];
    const float* Wq = (const float*)d_in[1];
    const float* Wk = (const float*)d_in[2];
    const float* Wv = (const float*)d_in[3];
    const float* Wo = (const float*)d_in[4];

    char* ws = (char*)d_ws;
    float* cosT = (float*)ws;                                   // 512 KB
    float* sinT = cosT + 2048 * 64;                             // 512 KB
    unsigned short* xh  = (unsigned short*)(ws + (1 << 20));    // 32 MB
    unsigned short* xl  = xh  + (size_t)16777216;               // 32 MB
    unsigned short* Wvh = xl  + (size_t)16777216;               // 8 MB (ws ~73 MB)

    // aliases (lifetimes disjoint): Vt overwrites xl after Q/K GEMMs;
    // attn_b overwrites xh after V GEMM.
    unsigned short* Vt     = xl;
    unsigned short* attn_b = xh;

    // d_out (67 MB fp32) hosts Qh/Kh until the final GEMM overwrites it
    unsigned short* Qh = (unsigned short*)d_out;
    unsigned short* Kh = Qh + (size_t)16777216;

    rope_tables<<<dim3(512), 256, 0, stream>>>(cosT, sinT);
    presplit<<<dim3(16384), 256, 0, stream>>>(x, xh, xl, 4194304);
    presplit<<<dim3(4096), 256, 0, stream>>>(Wv, Wvh, nullptr, 1048576);

    gemm2<0><<<dim3(16, 64), 256, 0, stream>>>(Wq, nullptr, xh, xl, Qh, cosT, sinT);
    gemm2<1><<<dim3(16, 64), 256, 0, stream>>>(Wk, nullptr, xh, xl, Kh, cosT, sinT);
    gemm2<2><<<dim3(64, 16), 256, 0, stream>>>(nullptr, xh, Wvh, nullptr, Vt, cosT, sinT);
    attn4<<<dim3(1024), 256, 0, stream>>>(Qh, Kh, Vt, attn_b);
    gemm2<3><<<dim3(16, 64), 256, 0, stream>>>(Wo, nullptr, attn_b, nullptr, d_out, cosT, sinT);
}

// Round 8
// 823.325 us; speedup vs baseline: 1.4769x; 1.1638x over previous
//
#include <hip/hip_runtime.h>

typedef float f32x4 __attribute__((ext_vector_type(4)));
typedef short bf16x8 __attribute__((ext_vector_type(8)));
typedef unsigned short u16x8 __attribute__((ext_vector_type(8)));
typedef unsigned short u16x4 __attribute__((ext_vector_type(4)));

#define KD 2048

static __device__ __forceinline__ unsigned short f2bf(float f) {
    __bf16 b = (__bf16)f;               // RNE
    return __builtin_bit_cast(unsigned short, b);
}
static __device__ __forceinline__ float bf2f(unsigned short h) {
    unsigned int u = ((unsigned int)h) << 16;
    return __builtin_bit_cast(float, u);
}
// async global->LDS, 16B per lane (dest = wave-uniform base + lane*16 linear;
// swizzles are applied on the GLOBAL source side)
static __device__ __forceinline__ void gl16(const unsigned short* g, unsigned short* l) {
    __builtin_amdgcn_global_load_lds(
        (const __attribute__((address_space(1))) unsigned int*)g,
        (__attribute__((address_space(3))) unsigned int*)l, 16, 0, 0);
}

// ---------------- RoPE tables ----------------
__global__ void rope_tables(float* __restrict__ cosT, float* __restrict__ sinT) {
    int i = blockIdx.x * 256 + threadIdx.x;          // 2048*64 entries
    if (i >= 2048 * 64) return;
    int s = i >> 6, j = i & 63;
    float freq = exp2f(-(2.0f * (float)j / 128.0f) * 13.287712379549449f);
    float a = (float)s * freq;
    cosT[i] = cosf(a);
    sinT[i] = sinf(a);
}

// ---------------- fp32 -> bf16 hi(/lo) split ----------------
__global__ void presplit(const float* __restrict__ src, unsigned short* __restrict__ dh,
                         unsigned short* __restrict__ dl, int n4) {
    int i = blockIdx.x * 256 + threadIdx.x;
    if (i >= n4) return;
    f32x4 v = ((const f32x4*)src)[i];
    u16x4 h, l;
#pragma unroll
    for (int j = 0; j < 4; ++j) {
        unsigned short hh = f2bf(v[j]);
        h[j] = hh;
        l[j] = f2bf(v[j] - bf2f(hh));
    }
    ((u16x4*)dh)[i] = h;
    if (dl) ((u16x4*)dl)[i] = l;
}

// ---------------- GEMM v3: D[i][j] = sum_k A[i][k]*B[j][k] ----------------
// T3-minimum schedule: stage(k+1) issued AFTER the cheap mid barrier, flies
// during compute(k); top-of-loop barrier is the only vmcnt drain per iter.
// B tiles (64B rows) XOR-swizzled chunk^=(row&3): 8-way -> 2-way (free).
// MODE 0: Q (A=Wq fp32 reg-split 3-term, B=xh/xl gload) -> RoPE+scale, Qh bf16
// MODE 1: K (A=Wk)                                      -> RoPE, Kh bf16
// MODE 2: V (A=xh gload, B=Wvh gload, 1-term)           -> Vt bf16 (B,H,dh,S)
// MODE 3: O (A=Wo fp32 reg hi, B=attn_b bf16, 1-term)   -> fp32 (B,S,D)
template<int MODE>
__global__ __launch_bounds__(256)
void gemm2(const float* __restrict__ Af, const unsigned short* __restrict__ Abf,
           const unsigned short* __restrict__ Bh_g, const unsigned short* __restrict__ Bl_g,
           void* __restrict__ OutH,
           const float* __restrict__ cosT, const float* __restrict__ sinT)
{
    constexpr bool SPLIT = (MODE <= 1);      // 3-term
    constexpr bool A_REG = (MODE != 2);      // A staged from fp32 via regs
    constexpr int  ASTR  = A_REG ? 40 : 32;  // reg-path tiles padded, gload linear
    constexpr int  NAB   = A_REG ? 1 : 2;    // A LDS buffers (gload path dbuf)

    const int bi = blockIdx.x, bj = blockIdx.y;
    const int tid = threadIdx.x;
    const int lane = tid & 63;
    const int w = tid >> 6;
    const int wm = w >> 1, wn = w & 1;
    const int lg = lane >> 4, lr = lane & 15;

    __shared__ unsigned short As_h[NAB][128 * ASTR];
    __shared__ unsigned short As_l[SPLIT ? 128 * 40 : 8];
    __shared__ unsigned short Bs_h[2][128 * 32];
    __shared__ unsigned short Bs_l[2][SPLIT ? 128 * 32 : 8];

    const int ra = tid >> 1;                  // 0..127
    const int ka = (tid & 1) * 16;            // 0 or 16
    const float* Ag = A_REG ? (Af + (size_t)(bi * 128 + ra) * KD + ka) : nullptr;

    f32x4 acc[4][4];
#pragma unroll
    for (int i = 0; i < 4; ++i)
#pragma unroll
        for (int j = 0; j < 4; ++j) acc[i][j] = f32x4{0.f, 0.f, 0.f, 0.f};

    f32x4 avA[4];
    auto loadA = [&](int k0) {
        if constexpr (A_REG) {
#pragma unroll
            for (int i = 0; i < 4; ++i) avA[i] = *(const f32x4*)(Ag + k0 + i * 4);
        }
    };
    auto writeA = [&]() {
        if constexpr (A_REG) {
            u16x8 h0, h1;
            if constexpr (SPLIT) {
                u16x8 l0, l1;
#pragma unroll
                for (int i = 0; i < 4; ++i) {
                    unsigned short h;
                    h = f2bf(avA[0][i]); h0[i]     = h; l0[i]     = f2bf(avA[0][i] - bf2f(h));
                    h = f2bf(avA[1][i]); h0[4 + i] = h; l0[4 + i] = f2bf(avA[1][i] - bf2f(h));
                    h = f2bf(avA[2][i]); h1[i]     = h; l1[i]     = f2bf(avA[2][i] - bf2f(h));
                    h = f2bf(avA[3][i]); h1[4 + i] = h; l1[4 + i] = f2bf(avA[3][i] - bf2f(h));
                }
                *(u16x8*)&As_l[ra * 40 + ka]     = l0;
                *(u16x8*)&As_l[ra * 40 + ka + 8] = l1;
            } else {
#pragma unroll
                for (int i = 0; i < 4; ++i) {
                    h0[i]     = f2bf(avA[0][i]);
                    h0[4 + i] = f2bf(avA[1][i]);
                    h1[i]     = f2bf(avA[2][i]);
                    h1[4 + i] = f2bf(avA[3][i]);
                }
            }
            *(u16x8*)&As_h[0][ra * 40 + ka]     = h0;
            *(u16x8*)&As_h[0][ra * 40 + ka + 8] = h1;
        }
    };
    auto stageB = [&](int k0, int buf) {
#pragma unroll
        for (int q2 = 0; q2 < 2; ++q2) {
            const int seg = w * 2 + q2;                 // 0..7
            const int row = seg * 16 + (lane >> 2);     // 0..127
            const int c   = (lane & 3) ^ (row & 3);     // T2 chunk swizzle
            const int loff = seg * 512 + lane * 8;      // shorts (linear dest)
            const size_t gs = (size_t)(bj * 128 + row) * KD + k0 + c * 8;
            gl16(Bh_g + gs, &Bs_h[buf][loff]);
            if constexpr (SPLIT) gl16(Bl_g + gs, &Bs_l[buf][loff]);
            if constexpr (!A_REG) {
                const size_t ga = (size_t)(bi * 128 + row) * KD + k0 + c * 8;
                gl16(Abf + ga, &As_h[buf][loff]);
            }
        }
    };
    auto term = [&](const unsigned short* As_, const unsigned short* Bs_, bool aswz) {
        const unsigned short* Ap = &As_[(wm * 64 + lr) * ASTR];
        const unsigned short* Bp = &Bs_[(wn * 64 + lr) * 32];
        const int aoff = aswz ? 8 * (lg ^ (lr & 3)) : lg * 8;
        const int boff = 8 * (lg ^ (lr & 3));
        bf16x8 af[4], bf[4];
#pragma unroll
        for (int i = 0; i < 4; ++i) {
            af[i] = *(const bf16x8*)(Ap + i * 16 * ASTR + aoff);
            bf[i] = *(const bf16x8*)(Bp + i * 16 * 32 + boff);
        }
#pragma unroll
        for (int mi = 0; mi < 4; ++mi)
#pragma unroll
            for (int ni = 0; ni < 4; ++ni)
                acc[mi][ni] = __builtin_amdgcn_mfma_f32_16x16x32_bf16(af[mi], bf[ni], acc[mi][ni], 0, 0, 0);
    };

    stageB(0, 0);
    loadA(0);
#pragma unroll 1
    for (int kt = 0; kt < 64; ++kt) {
        const int cur = kt & 1;
        __syncthreads();                 // drains stageB(kt); prev compute done
        if constexpr (A_REG) {
            writeA();                    // convert + ds_write (As now free)
            __syncthreads();             // cheap: only lgkm outstanding
        }
        if (kt < 63) {
            stageB((kt + 1) * 32, cur ^ 1);   // async; flies during compute
            loadA((kt + 1) * 32);             // reg loads; used next writeA
        }
        term(As_h[A_REG ? 0 : cur], Bs_h[cur], !A_REG);
        if constexpr (SPLIT) {
            term(As_h[0], Bs_l[cur], false);
            term(As_l,    Bs_h[cur], false);
        }
    }

    if constexpr (MODE <= 1) {
        unsigned short* OH = (unsigned short*)OutH;
        const float scale = (MODE == 0) ? 0.08838834764831845f : 1.0f;
#pragma unroll
        for (int mi = 0; mi < 4; ++mi) {
            int i0 = bi * 128 + wm * 64 + mi * 16 + lg * 4;  // dout, 4 consecutive
            int h = i0 >> 7, dd = i0 & 127;
            int jp = dd >> 1;
#pragma unroll
            for (int ni = 0; ni < 4; ++ni) {
                int jj = bj * 128 + wn * 64 + ni * 16 + lr;  // token
                int b = jj >> 11, s = jj & 2047;
                float c0 = cosT[s * 64 + jp],     s0 = sinT[s * 64 + jp];
                float c1 = cosT[s * 64 + jp + 1], s1 = sinT[s * 64 + jp + 1];
                f32x4 v = acc[mi][ni];
                float r0 = (v[0] * c0 - v[1] * s0) * scale;
                float r1 = (v[0] * s0 + v[1] * c0) * scale;
                float r2 = (v[2] * c1 - v[3] * s1) * scale;
                float r3 = (v[2] * s1 + v[3] * c1) * scale;
                u16x4 ph = { f2bf(r0), f2bf(r1), f2bf(r2), f2bf(r3) };
                *(u16x4*)&OH[((size_t)(b * 16 + h) * 2048 + s) * 128 + dd] = ph;
            }
        }
    } else if constexpr (MODE == 2) {
        unsigned short* O = (unsigned short*)OutH;
#pragma unroll
        for (int mi = 0; mi < 4; ++mi) {
            int i0 = bi * 128 + wm * 64 + mi * 16 + lg * 4;  // token, 4 consecutive
            int b = i0 >> 11, s = i0 & 2047;
#pragma unroll
            for (int ni = 0; ni < 4; ++ni) {
                int jj = bj * 128 + wn * 64 + ni * 16 + lr;  // dout
                int h = jj >> 7, dd = jj & 127;
                f32x4 v = acc[mi][ni];
                u16x4 pk = { f2bf(v[0]), f2bf(v[1]), f2bf(v[2]), f2bf(v[3]) };
                *(u16x4*)&O[((size_t)(b * 16 + h) * 128 + dd) * 2048 + s] = pk;
            }
        }
    } else {
        float* O = (float*)OutH;
#pragma unroll
        for (int mi = 0; mi < 4; ++mi) {
            int i0 = bi * 128 + wm * 64 + mi * 16 + lg * 4;  // dout, 4 consecutive
#pragma unroll
            for (int ni = 0; ni < 4; ++ni) {
                int jj = bj * 128 + wn * 64 + ni * 16 + lr;  // token
                *(f32x4*)&O[(size_t)jj * 2048 + i0] = acc[mi][ni];
            }
        }
    }
}

// ---------------- causal flash attention v5 ----------------
// r5's proven structure (4 waves x 32 q-rows, full d, plain bounds) +
// 1-term QK^T + balanced qt pairing + verified swizzles + defer-max.
// 512 blocks = 64 bh x 8 p; block p does qt=15-p then qt=p -> 68 iters const,
// 512 = 256CU x 2 resident: one balanced batch.
__global__ __launch_bounds__(256)
void attn5(const unsigned short* __restrict__ Qh, const unsigned short* __restrict__ Kh,
           const unsigned short* __restrict__ Vt, unsigned short* __restrict__ Ob)
{
    const int bid = blockIdx.x;
    const int bh = bid & 63;
    const int p  = bid >> 6;                 // 0..7
    const int tid = threadIdx.x;
    const int lane = tid & 63, w = tid >> 6;
    const int lg = lane >> 4, lr = lane & 15;
    const int b = bh >> 4, h = bh & 15;

    __shared__ unsigned short Ks[2][32 * 128];   // 8KB x2, swizzled ^(row&7)
    __shared__ unsigned short Vs[2][128 * 32];   // 8KB x2, swizzled ^((row>>1)&3)
    __shared__ unsigned short Ps[4][16 * 40];    // per-wave P relay, stride 40

    auto stage = [&](int t) {
        const int buf = t & 1;
        const int kv0 = t * 32;
#pragma unroll
        for (int q2 = 0; q2 < 2; ++q2) {
            const int seg = w * 2 + q2;                      // 0..7
            {   // K: 256B rows, chunk ^ (row&7)
                const int row = seg * 4 + (lane >> 4);
                const int gcol = 8 * ((lane & 15) ^ (row & 7));
                gl16(Kh + ((size_t)bh * 2048 + kv0 + row) * 128 + gcol,
                     &Ks[buf][seg * 512 + lane * 8]);
            }
            {   // V: 64B rows, chunk ^ ((row>>1)&3)
                const int row = seg * 16 + (lane >> 2);      // d 0..127
                const int gcol = 8 * ((lane & 3) ^ ((row >> 1) & 3));
                gl16(Vt + ((size_t)bh * 128 + row) * 2048 + kv0 + gcol,
                     &Vs[buf][seg * 512 + lane * 8]);
            }
        }
    };

#pragma unroll 1
    for (int half = 0; half < 2; ++half) {
        const int qt = half ? p : (15 - p);          // 128-row q-tile index
        const int qbase = qt * 128 + w * 32;
        const int qmaxw = qbase + 31;
        const int nkv = 4 * (qt + 1);

        bf16x8 qf[2][4];
#pragma unroll
        for (int qg = 0; qg < 2; ++qg) {
            const size_t qoff = ((size_t)bh * 2048 + qbase + qg * 16 + lr) * 128;
#pragma unroll
            for (int kk = 0; kk < 4; ++kk)
                qf[qg][kk] = *(const bf16x8*)(Qh + qoff + kk * 32 + lg * 8);
        }

        f32x4 o[8][2];
#pragma unroll
        for (int i = 0; i < 8; ++i)
#pragma unroll
            for (int qg = 0; qg < 2; ++qg) o[i][qg] = f32x4{0.f, 0.f, 0.f, 0.f};
        float m_run[2] = { -1e30f, -1e30f }, l_run[2] = { 0.f, 0.f };

        stage(0);
        __syncthreads();

#pragma unroll 1
        for (int t = 0; t < nkv; ++t) {
            if (t + 1 < nkv) stage(t + 1);       // issue-early into other buffer
            const int buf = t & 1;
            const int kv0 = t * 32;
            if (kv0 <= qmaxw) {
                // QK^T swapped, 1-term: D[kv][q]; lane: q=lr, kv=m2*16+lg*4+rr
                f32x4 sc[2][2];
#pragma unroll
                for (int m2 = 0; m2 < 2; ++m2)
#pragma unroll
                    for (int qg = 0; qg < 2; ++qg) sc[m2][qg] = f32x4{0.f, 0.f, 0.f, 0.f};
#pragma unroll
                for (int m2 = 0; m2 < 2; ++m2)
#pragma unroll
                    for (int kk = 0; kk < 4; ++kk) {
                        const int go = 8 * ((4 * kk + lg) ^ (lr & 7));
                        bf16x8 kf = *(const bf16x8*)&Ks[buf][(m2 * 16 + lr) * 128 + go];
#pragma unroll
                        for (int qg = 0; qg < 2; ++qg)
                            sc[m2][qg] = __builtin_amdgcn_mfma_f32_16x16x32_bf16(kf, qf[qg][kk], sc[m2][qg], 0, 0, 0);
                    }
#pragma unroll
                for (int qg = 0; qg < 2; ++qg) {
                    const int q = qbase + qg * 16 + lr;
                    float pmax = -1e30f;
#pragma unroll
                    for (int m2 = 0; m2 < 2; ++m2)
#pragma unroll
                        for (int rr = 0; rr < 4; ++rr) {
                            int kvg = kv0 + m2 * 16 + lg * 4 + rr;
                            float sv = (kvg <= q) ? sc[m2][qg][rr] : -1e30f;
                            sc[m2][qg][rr] = sv;
                            pmax = fmaxf(pmax, sv);
                        }
                    pmax = fmaxf(pmax, __shfl_xor(pmax, 16));
                    pmax = fmaxf(pmax, __shfl_xor(pmax, 32));
                    // T13 defer-max: skip rescale unless max grew past THR=8
                    if (!__all(pmax <= m_run[qg] + 8.0f)) {
                        float mnew = fmaxf(m_run[qg], pmax);
                        float alpha = __expf(m_run[qg] - mnew);
                        m_run[qg] = mnew;
                        l_run[qg] *= alpha;
#pragma unroll
                        for (int ni = 0; ni < 8; ++ni) {
                            o[ni][qg][0] *= alpha; o[ni][qg][1] *= alpha;
                            o[ni][qg][2] *= alpha; o[ni][qg][3] *= alpha;
                        }
                    }
                    float psum = 0.f;
                    u16x4 pq[2];
#pragma unroll
                    for (int m2 = 0; m2 < 2; ++m2)
#pragma unroll
                        for (int rr = 0; rr < 4; ++rr) {
                            float pv = __expf(sc[m2][qg][rr] - m_run[qg]);
                            unsigned short ph = f2bf(pv);
                            pq[m2][rr] = ph;
                            psum += bf2f(ph);    // consistent with PV numerator
                        }
                    l_run[qg] += psum;
                    // P relay: C-layout -> B-frag via per-wave LDS (stride 40)
                    *(u16x4*)&Ps[w][lr * 40 + lg * 4]      = pq[0];
                    *(u16x4*)&Ps[w][lr * 40 + 16 + lg * 4] = pq[1];
                    bf16x8 pf = *(const bf16x8*)&Ps[w][lr * 40 + lg * 8];
                    // PV swapped: O^T[d][q], A = Vt rows (d), B = P (K=32)
#pragma unroll
                    for (int ni = 0; ni < 8; ++ni) {
                        bf16x8 vf = *(const bf16x8*)&Vs[buf][(ni * 16 + lr) * 32 + 8 * (lg ^ ((lr >> 1) & 3))];
                        o[ni][qg] = __builtin_amdgcn_mfma_f32_16x16x32_bf16(vf, pf, o[ni][qg], 0, 0, 0);
                    }
                }
            }
            __syncthreads();
        }

#pragma unroll
        for (int qg = 0; qg < 2; ++qg) {
            float l = l_run[qg];
            l += __shfl_xor(l, 16);
            l += __shfl_xor(l, 32);
            float inv = 1.f / l;
            const int q = qbase + qg * 16 + lr;
            unsigned short* Op = Ob + (((size_t)(b * 2048 + q) * 16 + h) * 128);
#pragma unroll
            for (int ni = 0; ni < 8; ++ni) {
                u16x4 pk = { f2bf(o[ni][qg][0] * inv), f2bf(o[ni][qg][1] * inv),
                             f2bf(o[ni][qg][2] * inv), f2bf(o[ni][qg][3] * inv) };
                *(u16x4*)&Op[ni * 16 + lg * 4] = pk;
            }
        }
    }
}

extern "C" void kernel_launch(void* const* d_in, const int* in_sizes, int n_in,
                              void* d_out, int out_size, void* d_ws, size_t ws_size,
                              hipStream_t stream) {
    const float* x  = (const float*)d_in[0];
    const float* Wq = (const float*)d_in[1];
    const float* Wk = (const float*)d_in[2];
    const float* Wv = (const float*)d_in[3];
    const float* Wo = (const float*)d_in[4];

    char* ws = (char*)d_ws;
    float* cosT = (float*)ws;                                   // 512 KB
    float* sinT = cosT + 2048 * 64;                             // 512 KB
    unsigned short* xh  = (unsigned short*)(ws + (1 << 20));    // 32 MB
    unsigned short* xl  = xh  + (size_t)16777216;               // 32 MB
    unsigned short* Wvh = xl  + (size_t)16777216;               // 8 MB (ws ~73 MB)

    // aliases (lifetimes disjoint): Vt overwrites xl after Q/K GEMMs;
    // attn_b overwrites xh after V GEMM.
    unsigned short* Vt     = xl;
    unsigned short* attn_b = xh;

    // d_out (67 MB fp32) hosts Qh/Kh until the final GEMM overwrites it
    unsigned short* Qh = (unsigned short*)d_out;
    unsigned short* Kh = Qh + (size_t)16777216;

    rope_tables<<<dim3(512), 256, 0, stream>>>(cosT, sinT);
    presplit<<<dim3(16384), 256, 0, stream>>>(x, xh, xl, 4194304);
    presplit<<<dim3(4096), 256, 0, stream>>>(Wv, Wvh, nullptr, 1048576);

    gemm2<0><<<dim3(16, 64), 256, 0, stream>>>(Wq, nullptr, xh, xl, Qh, cosT, sinT);
    gemm2<1><<<dim3(16, 64), 256, 0, stream>>>(Wk, nullptr, xh, xl, Kh, cosT, sinT);
    gemm2<2><<<dim3(64, 16), 256, 0, stream>>>(nullptr, xh, Wvh, nullptr, Vt, cosT, sinT);
    attn5<<<dim3(512), 256, 0, stream>>>(Qh, Kh, Vt, attn_b);
    gemm2<3><<<dim3(16, 64), 256, 0, stream>>>(Wo, nullptr, attn_b, nullptr, d_out, cosT, sinT);
}

// Round 9
// 757.293 us; speedup vs baseline: 1.6057x; 1.0872x over previous
//
#include <hip/hip_runtime.h>

typedef float f32x4 __attribute__((ext_vector_type(4)));
typedef short bf16x8 __attribute__((ext_vector_type(8)));
typedef unsigned short u16x8 __attribute__((ext_vector_type(8)));
typedef unsigned short u16x4 __attribute__((ext_vector_type(4)));

#define KD 2048

static __device__ __forceinline__ unsigned short f2bf(float f) {
    __bf16 b = (__bf16)f;               // RNE
    return __builtin_bit_cast(unsigned short, b);
}
static __device__ __forceinline__ float bf2f(unsigned short h) {
    unsigned int u = ((unsigned int)h) << 16;
    return __builtin_bit_cast(float, u);
}
// async global->LDS, 16B per lane (dest = wave-uniform base + lane*16 linear;
// swizzles are applied on the GLOBAL source side)
static __device__ __forceinline__ void gl16(const unsigned short* g, unsigned short* l) {
    __builtin_amdgcn_global_load_lds(
        (const __attribute__((address_space(1))) unsigned int*)g,
        (__attribute__((address_space(3))) unsigned int*)l, 16, 0, 0);
}

// ---------------- RoPE tables ----------------
__global__ void rope_tables(float* __restrict__ cosT, float* __restrict__ sinT) {
    int i = blockIdx.x * 256 + threadIdx.x;          // 2048*64 entries
    if (i >= 2048 * 64) return;
    int s = i >> 6, j = i & 63;
    float freq = exp2f(-(2.0f * (float)j / 128.0f) * 13.287712379549449f);
    float a = (float)s * freq;
    cosT[i] = cosf(a);
    sinT[i] = sinf(a);
}

// ---------------- fp32 -> bf16 hi(/lo) split ----------------
__global__ void presplit(const float* __restrict__ src, unsigned short* __restrict__ dh,
                         unsigned short* __restrict__ dl, int n4) {
    int i = blockIdx.x * 256 + threadIdx.x;
    if (i >= n4) return;
    f32x4 v = ((const f32x4*)src)[i];
    u16x4 h, l;
#pragma unroll
    for (int j = 0; j < 4; ++j) {
        unsigned short hh = f2bf(v[j]);
        h[j] = hh;
        l[j] = f2bf(v[j] - bf2f(hh));
    }
    ((u16x4*)dh)[i] = h;
    if (dl) ((u16x4*)dl)[i] = l;
}

// ---------------- GEMM v4: D[i][j] = sum_k A[i][k]*B[j][k], all-gload -------
// All operands pre-split bf16 in HBM; every tile staged via global_load_lds
// (no VALU convert, no ds_write, single barrier per K-step, dbuf).
// Tile layout: 128 rows x 32 k (64B rows); source-swizzled chunk
// (lane&3)^((lane>>4)&3); read chunk lg^((lr>>2)&3) -> 2-way (free).
// MODE 0: Q (A=Wqh/Wql, B=xh/xl, 3-term) -> RoPE+scale, Qh bf16 (B,H,S,dh)
// MODE 1: K (A=Wkh/Wkl, B=xh/xl, 3-term) -> RoPE, Kh bf16
// MODE 2: V (A=xh, B=Wvh, 1-term)        -> Vt bf16 (B,H,dh,S)
// MODE 3: O (A=Woh, B=attn_b, 1-term)    -> fp32 (B,S,D)
template<int MODE>
__global__ __launch_bounds__(256)
void gemm3(const unsigned short* __restrict__ Ah, const unsigned short* __restrict__ Al,
           const unsigned short* __restrict__ Bh, const unsigned short* __restrict__ Bl,
           void* __restrict__ OutH,
           const float* __restrict__ cosT, const float* __restrict__ sinT)
{
    constexpr bool SPLIT = (MODE <= 1);      // 3-term

    const int bi = blockIdx.x, bj = blockIdx.y;
    const int tid = threadIdx.x;
    const int lane = tid & 63;
    const int w = tid >> 6;
    const int wm = w >> 1, wn = w & 1;
    const int lg = lane >> 4, lr = lane & 15;

    __shared__ unsigned short As_h[2][128 * 32];
    __shared__ unsigned short Bs_h[2][128 * 32];
    __shared__ unsigned short As_l[SPLIT ? 2 : 1][SPLIT ? 128 * 32 : 8];
    __shared__ unsigned short Bs_l[SPLIT ? 2 : 1][SPLIT ? 128 * 32 : 8];

    f32x4 acc[4][4];
#pragma unroll
    for (int i = 0; i < 4; ++i)
#pragma unroll
        for (int j = 0; j < 4; ++j) acc[i][j] = f32x4{0.f, 0.f, 0.f, 0.f};

    // staging geometry: row = seg*16 + lane>>2, source chunk swizzled
    const int srow = lane >> 2;
    const int schk = (lane & 3) ^ ((lane >> 4) & 3);

    auto stage = [&](int k0, int buf) {
#pragma unroll
        for (int q2 = 0; q2 < 2; ++q2) {
            const int seg = w * 2 + q2;                 // 0..7
            const int row = seg * 16 + srow;            // 0..127
            const int loff = seg * 512 + lane * 8;      // shorts (linear dest)
            const size_t ga = (size_t)(bi * 128 + row) * KD + k0 + schk * 8;
            const size_t gb = (size_t)(bj * 128 + row) * KD + k0 + schk * 8;
            gl16(Ah + ga, &As_h[buf][loff]);
            gl16(Bh + gb, &Bs_h[buf][loff]);
            if constexpr (SPLIT) {
                gl16(Al + ga, &As_l[buf][loff]);
                gl16(Bl + gb, &Bs_l[buf][loff]);
            }
        }
    };
    const int roff = 8 * (lg ^ ((lr >> 2) & 3));        // read chunk (2-way)
    auto term = [&](const unsigned short* A_, const unsigned short* B_) {
        const unsigned short* Ap = A_ + (wm * 64 + lr) * 32;
        const unsigned short* Bp = B_ + (wn * 64 + lr) * 32;
        bf16x8 af[4], bf[4];
#pragma unroll
        for (int i = 0; i < 4; ++i) {
            af[i] = *(const bf16x8*)(Ap + i * 512 + roff);
            bf[i] = *(const bf16x8*)(Bp + i * 512 + roff);
        }
#pragma unroll
        for (int mi = 0; mi < 4; ++mi)
#pragma unroll
            for (int ni = 0; ni < 4; ++ni)
                acc[mi][ni] = __builtin_amdgcn_mfma_f32_16x16x32_bf16(af[mi], bf[ni], acc[mi][ni], 0, 0, 0);
    };

    stage(0, 0);
#pragma unroll 1
    for (int kt = 0; kt < 64; ++kt) {
        const int cur = kt & 1;
        __syncthreads();                      // stage(kt) landed; prev compute done
        if (kt < 63) stage((kt + 1) * 32, cur ^ 1);   // flies during compute
        term(As_h[cur], Bs_h[cur]);
        if constexpr (SPLIT) {
            term(As_h[cur], Bs_l[cur]);
            term(As_l[cur], Bs_h[cur]);
        }
    }

    if constexpr (MODE <= 1) {
        unsigned short* OH = (unsigned short*)OutH;
        const float scale = (MODE == 0) ? 0.08838834764831845f : 1.0f;
#pragma unroll
        for (int mi = 0; mi < 4; ++mi) {
            int i0 = bi * 128 + wm * 64 + mi * 16 + lg * 4;  // dout, 4 consecutive
            int h = i0 >> 7, dd = i0 & 127;
            int jp = dd >> 1;
#pragma unroll
            for (int ni = 0; ni < 4; ++ni) {
                int jj = bj * 128 + wn * 64 + ni * 16 + lr;  // token
                int b = jj >> 11, s = jj & 2047;
                float c0 = cosT[s * 64 + jp],     s0 = sinT[s * 64 + jp];
                float c1 = cosT[s * 64 + jp + 1], s1 = sinT[s * 64 + jp + 1];
                f32x4 v = acc[mi][ni];
                float r0 = (v[0] * c0 - v[1] * s0) * scale;
                float r1 = (v[0] * s0 + v[1] * c0) * scale;
                float r2 = (v[2] * c1 - v[3] * s1) * scale;
                float r3 = (v[2] * s1 + v[3] * c1) * scale;
                u16x4 ph = { f2bf(r0), f2bf(r1), f2bf(r2), f2bf(r3) };
                *(u16x4*)&OH[((size_t)(b * 16 + h) * 2048 + s) * 128 + dd] = ph;
            }
        }
    } else if constexpr (MODE == 2) {
        unsigned short* O = (unsigned short*)OutH;
#pragma unroll
        for (int mi = 0; mi < 4; ++mi) {
            int i0 = bi * 128 + wm * 64 + mi * 16 + lg * 4;  // token, 4 consecutive
            int b = i0 >> 11, s = i0 & 2047;
#pragma unroll
            for (int ni = 0; ni < 4; ++ni) {
                int jj = bj * 128 + wn * 64 + ni * 16 + lr;  // dout
                int h = jj >> 7, dd = jj & 127;
                f32x4 v = acc[mi][ni];
                u16x4 pk = { f2bf(v[0]), f2bf(v[1]), f2bf(v[2]), f2bf(v[3]) };
                *(u16x4*)&O[((size_t)(b * 16 + h) * 128 + dd) * 2048 + s] = pk;
            }
        }
    } else {
        float* O = (float*)OutH;
#pragma unroll
        for (int mi = 0; mi < 4; ++mi) {
            int i0 = bi * 128 + wm * 64 + mi * 16 + lg * 4;  // dout, 4 consecutive
#pragma unroll
            for (int ni = 0; ni < 4; ++ni) {
                int jj = bj * 128 + wn * 64 + ni * 16 + lr;  // token
                *(f32x4*)&O[(size_t)jj * 2048 + i0] = acc[mi][ni];
            }
        }
    }
}

// ---------------- causal flash attention v5 (unchanged from r8) -------------
// 512 blocks = 64 bh x 8 p; block p does qt=15-p then qt=p -> 68 iters const.
__global__ __launch_bounds__(256)
void attn5(const unsigned short* __restrict__ Qh, const unsigned short* __restrict__ Kh,
           const unsigned short* __restrict__ Vt, unsigned short* __restrict__ Ob)
{
    const int bid = blockIdx.x;
    const int bh = bid & 63;
    const int p  = bid >> 6;                 // 0..7
    const int tid = threadIdx.x;
    const int lane = tid & 63, w = tid >> 6;
    const int lg = lane >> 4, lr = lane & 15;
    const int b = bh >> 4, h = bh & 15;

    __shared__ unsigned short Ks[2][32 * 128];   // 8KB x2, swizzled ^(row&7)
    __shared__ unsigned short Vs[2][128 * 32];   // 8KB x2, swizzled ^((row>>1)&3)
    __shared__ unsigned short Ps[4][16 * 40];    // per-wave P relay, stride 40

    auto stage = [&](int t) {
        const int buf = t & 1;
        const int kv0 = t * 32;
#pragma unroll
        for (int q2 = 0; q2 < 2; ++q2) {
            const int seg = w * 2 + q2;                      // 0..7
            {   // K: 256B rows, chunk ^ (row&7)
                const int row = seg * 4 + (lane >> 4);
                const int gcol = 8 * ((lane & 15) ^ (row & 7));
                gl16(Kh + ((size_t)bh * 2048 + kv0 + row) * 128 + gcol,
                     &Ks[buf][seg * 512 + lane * 8]);
            }
            {   // V: 64B rows, chunk ^ ((row>>1)&3)
                const int row = seg * 16 + (lane >> 2);      // d 0..127
                const int gcol = 8 * ((lane & 3) ^ ((row >> 1) & 3));
                gl16(Vt + ((size_t)bh * 128 + row) * 2048 + kv0 + gcol,
                     &Vs[buf][seg * 512 + lane * 8]);
            }
        }
    };

#pragma unroll 1
    for (int half = 0; half < 2; ++half) {
        const int qt = half ? p : (15 - p);          // 128-row q-tile index
        const int qbase = qt * 128 + w * 32;
        const int qmaxw = qbase + 31;
        const int nkv = 4 * (qt + 1);

        bf16x8 qf[2][4];
#pragma unroll
        for (int qg = 0; qg < 2; ++qg) {
            const size_t qoff = ((size_t)bh * 2048 + qbase + qg * 16 + lr) * 128;
#pragma unroll
            for (int kk = 0; kk < 4; ++kk)
                qf[qg][kk] = *(const bf16x8*)(Qh + qoff + kk * 32 + lg * 8);
        }

        f32x4 o[8][2];
#pragma unroll
        for (int i = 0; i < 8; ++i)
#pragma unroll
            for (int qg = 0; qg < 2; ++qg) o[i][qg] = f32x4{0.f, 0.f, 0.f, 0.f};
        float m_run[2] = { -1e30f, -1e30f }, l_run[2] = { 0.f, 0.f };

        stage(0);
        __syncthreads();

#pragma unroll 1
        for (int t = 0; t < nkv; ++t) {
            if (t + 1 < nkv) stage(t + 1);       // issue-early into other buffer
            const int buf = t & 1;
            const int kv0 = t * 32;
            if (kv0 <= qmaxw) {
                // QK^T swapped, 1-term: D[kv][q]; lane: q=lr, kv=m2*16+lg*4+rr
                f32x4 sc[2][2];
#pragma unroll
                for (int m2 = 0; m2 < 2; ++m2)
#pragma unroll
                    for (int qg = 0; qg < 2; ++qg) sc[m2][qg] = f32x4{0.f, 0.f, 0.f, 0.f};
#pragma unroll
                for (int m2 = 0; m2 < 2; ++m2)
#pragma unroll
                    for (int kk = 0; kk < 4; ++kk) {
                        const int go = 8 * ((4 * kk + lg) ^ (lr & 7));
                        bf16x8 kf = *(const bf16x8*)&Ks[buf][(m2 * 16 + lr) * 128 + go];
#pragma unroll
                        for (int qg = 0; qg < 2; ++qg)
                            sc[m2][qg] = __builtin_amdgcn_mfma_f32_16x16x32_bf16(kf, qf[qg][kk], sc[m2][qg], 0, 0, 0);
                    }
#pragma unroll
                for (int qg = 0; qg < 2; ++qg) {
                    const int q = qbase + qg * 16 + lr;
                    float pmax = -1e30f;
#pragma unroll
                    for (int m2 = 0; m2 < 2; ++m2)
#pragma unroll
                        for (int rr = 0; rr < 4; ++rr) {
                            int kvg = kv0 + m2 * 16 + lg * 4 + rr;
                            float sv = (kvg <= q) ? sc[m2][qg][rr] : -1e30f;
                            sc[m2][qg][rr] = sv;
                            pmax = fmaxf(pmax, sv);
                        }
                    pmax = fmaxf(pmax, __shfl_xor(pmax, 16));
                    pmax = fmaxf(pmax, __shfl_xor(pmax, 32));
                    // T13 defer-max: skip rescale unless max grew past THR=8
                    if (!__all(pmax <= m_run[qg] + 8.0f)) {
                        float mnew = fmaxf(m_run[qg], pmax);
                        float alpha = __expf(m_run[qg] - mnew);
                        m_run[qg] = mnew;
                        l_run[qg] *= alpha;
#pragma unroll
                        for (int ni = 0; ni < 8; ++ni) {
                            o[ni][qg][0] *= alpha; o[ni][qg][1] *= alpha;
                            o[ni][qg][2] *= alpha; o[ni][qg][3] *= alpha;
                        }
                    }
                    float psum = 0.f;
                    u16x4 pq[2];
#pragma unroll
                    for (int m2 = 0; m2 < 2; ++m2)
#pragma unroll
                        for (int rr = 0; rr < 4; ++rr) {
                            float pv = __expf(sc[m2][qg][rr] - m_run[qg]);
                            unsigned short ph = f2bf(pv);
                            pq[m2][rr] = ph;
                            psum += bf2f(ph);    // consistent with PV numerator
                        }
                    l_run[qg] += psum;
                    // P relay: C-layout -> B-frag via per-wave LDS (stride 40)
                    *(u16x4*)&Ps[w][lr * 40 + lg * 4]      = pq[0];
                    *(u16x4*)&Ps[w][lr * 40 + 16 + lg * 4] = pq[1];
                    bf16x8 pf = *(const bf16x8*)&Ps[w][lr * 40 + lg * 8];
                    // PV swapped: O^T[d][q], A = Vt rows (d), B = P (K=32)
#pragma unroll
                    for (int ni = 0; ni < 8; ++ni) {
                        bf16x8 vf = *(const bf16x8*)&Vs[buf][(ni * 16 + lr) * 32 + 8 * (lg ^ ((lr >> 1) & 3))];
                        o[ni][qg] = __builtin_amdgcn_mfma_f32_16x16x32_bf16(vf, pf, o[ni][qg], 0, 0, 0);
                    }
                }
            }
            __syncthreads();
        }

#pragma unroll
        for (int qg = 0; qg < 2; ++qg) {
            float l = l_run[qg];
            l += __shfl_xor(l, 16);
            l += __shfl_xor(l, 32);
            float inv = 1.f / l;
            const int q = qbase + qg * 16 + lr;
            unsigned short* Op = Ob + (((size_t)(b * 2048 + q) * 16 + h) * 128);
#pragma unroll
            for (int ni = 0; ni < 8; ++ni) {
                u16x4 pk = { f2bf(o[ni][qg][0] * inv), f2bf(o[ni][qg][1] * inv),
                             f2bf(o[ni][qg][2] * inv), f2bf(o[ni][qg][3] * inv) };
                *(u16x4*)&Op[ni * 16 + lg * 4] = pk;
            }
        }
    }
}

extern "C" void kernel_launch(void* const* d_in, const int* in_sizes, int n_in,
                              void* d_out, int out_size, void* d_ws, size_t ws_size,
                              hipStream_t stream) {
    const float* x  = (const float*)d_in[0];
    const float* Wq = (const float*)d_in[1];
    const float* Wk = (const float*)d_in[2];
    const float* Wv = (const float*)d_in[3];
    const float* Wo = (const float*)d_in[4];

    char* ws = (char*)d_ws;
    float* cosT = (float*)ws;                                   // 512 KB
    float* sinT = cosT + 2048 * 64;                             // 512 KB
    unsigned short* xh  = (unsigned short*)(ws + (1 << 20));    // 32 MB
    unsigned short* xl  = xh  + (size_t)16777216;               // 32 MB
    unsigned short* Wvh = xl  + (size_t)16777216;               // 8 MB
    unsigned short* Wqh = Wvh + (size_t)4194304;                // 8 MB
    unsigned short* Wql = Wqh + (size_t)4194304;                // 8 MB
    unsigned short* Wkh = Wql + (size_t)4194304;                // 8 MB
    unsigned short* Wkl = Wkh + (size_t)4194304;                // 8 MB
    unsigned short* Woh = Wkl + (size_t)4194304;                // 8 MB (ws ~113 MB)

    // aliases (lifetimes disjoint): Vt overwrites xl after Q/K GEMMs;
    // attn_b overwrites xh after V GEMM.
    unsigned short* Vt     = xl;
    unsigned short* attn_b = xh;

    // d_out (67 MB fp32) hosts Qh/Kh until the final GEMM overwrites it
    unsigned short* Qh = (unsigned short*)d_out;
    unsigned short* Kh = Qh + (size_t)16777216;

    rope_tables<<<dim3(512), 256, 0, stream>>>(cosT, sinT);
    presplit<<<dim3(16384), 256, 0, stream>>>(x, xh, xl, 4194304);
    presplit<<<dim3(4096), 256, 0, stream>>>(Wq, Wqh, Wql, 1048576);
    presplit<<<dim3(4096), 256, 0, stream>>>(Wk, Wkh, Wkl, 1048576);
    presplit<<<dim3(4096), 256, 0, stream>>>(Wv, Wvh, nullptr, 1048576);
    presplit<<<dim3(4096), 256, 0, stream>>>(Wo, Woh, nullptr, 1048576);

    gemm3<0><<<dim3(16, 64), 256, 0, stream>>>(Wqh, Wql, xh, xl, Qh, cosT, sinT);
    gemm3<1><<<dim3(16, 64), 256, 0, stream>>>(Wkh, Wkl, xh, xl, Kh, cosT, sinT);
    gemm3<2><<<dim3(64, 16), 256, 0, stream>>>(xh, nullptr, Wvh, nullptr, Vt, cosT, sinT);
    attn5<<<dim3(512), 256, 0, stream>>>(Qh, Kh, Vt, attn_b);
    gemm3<3><<<dim3(16, 64), 256, 0, stream>>>(Woh, nullptr, attn_b, nullptr, d_out, cosT, sinT);
}

// Round 10
// 571.824 us; speedup vs baseline: 2.1265x; 1.3243x over previous
//
#include <hip/hip_runtime.h>

typedef float f32x4 __attribute__((ext_vector_type(4)));
typedef _Float16 f16x8 __attribute__((ext_vector_type(8)));
typedef unsigned short u16x8 __attribute__((ext_vector_type(8)));
typedef unsigned short u16x4 __attribute__((ext_vector_type(4)));

#define KD 2048

static __device__ __forceinline__ unsigned short f2h(float f) {
    _Float16 h = (_Float16)f;           // RNE
    return __builtin_bit_cast(unsigned short, h);
}
static __device__ __forceinline__ float h2f(unsigned short u) {
    return (float)__builtin_bit_cast(_Float16, u);
}
// async global->LDS, 16B per lane (dest = wave-uniform base + lane*16 linear;
// swizzles are applied on the GLOBAL source side)
static __device__ __forceinline__ void gl16(const unsigned short* g, unsigned short* l) {
    __builtin_amdgcn_global_load_lds(
        (const __attribute__((address_space(1))) unsigned int*)g,
        (__attribute__((address_space(3))) unsigned int*)l, 16, 0, 0);
}

// ---------------- RoPE tables ----------------
__global__ void rope_tables(float* __restrict__ cosT, float* __restrict__ sinT) {
    int i = blockIdx.x * 256 + threadIdx.x;          // 2048*64 entries
    if (i >= 2048 * 64) return;
    int s = i >> 6, j = i & 63;
    float freq = exp2f(-(2.0f * (float)j / 128.0f) * 13.287712379549449f);
    float a = (float)s * freq;
    cosT[i] = cosf(a);
    sinT[i] = sinf(a);
}

// ---------------- fp32 -> fp16 convert ----------------
__global__ void precvt(const float* __restrict__ src, unsigned short* __restrict__ dst, int n4) {
    int i = blockIdx.x * 256 + threadIdx.x;
    if (i >= n4) return;
    f32x4 v = ((const f32x4*)src)[i];
    u16x4 h = { f2h(v[0]), f2h(v[1]), f2h(v[2]), f2h(v[3]) };
    ((u16x4*)dst)[i] = h;
}
// 4 weight matrices in one launch (blockIdx.y selects)
__global__ void precvtW(const float* __restrict__ s0, const float* __restrict__ s1,
                        const float* __restrict__ s2, const float* __restrict__ s3,
                        unsigned short* __restrict__ d0, unsigned short* __restrict__ d1,
                        unsigned short* __restrict__ d2, unsigned short* __restrict__ d3) {
    int i = blockIdx.x * 256 + threadIdx.x;          // n4 = 1048576
    if (i >= 1048576) return;
    const float* s = blockIdx.y == 0 ? s0 : blockIdx.y == 1 ? s1 : blockIdx.y == 2 ? s2 : s3;
    unsigned short* d = blockIdx.y == 0 ? d0 : blockIdx.y == 1 ? d1 : blockIdx.y == 2 ? d2 : d3;
    f32x4 v = ((const f32x4*)s)[i];
    u16x4 h = { f2h(v[0]), f2h(v[1]), f2h(v[2]), f2h(v[3]) };
    ((u16x4*)d)[i] = h;
}

// ---------------- GEMM v5: D[i][j] = sum_k A[i][k]*B[j][k], fp16 1-term ------
// All operands fp16 in HBM, staged via global_load_lds (2-phase dbuf, one
// barrier per K-step). Tile 128x32 (64B rows); source chunk swizzled
// (lane&3)^((lane>>4)&3); read chunk lg^((lr>>2)&3) -> 2-way (free).
// MODE 0: Q (A=Wqh, B=xh) -> RoPE+scale, Qh fp16 (B,H,S,dh)
// MODE 1: K (A=Wkh, B=xh) -> RoPE, Kh fp16
// MODE 2: V (A=xh, B=Wvh) -> Vt fp16 (B,H,dh,S)
// MODE 3: O (A=Woh, B=attn_b) -> fp32 (B,S,D)
template<int MODE>
__global__ __launch_bounds__(256)
void gemm4(const unsigned short* __restrict__ Ah, const unsigned short* __restrict__ Bh,
           void* __restrict__ OutH,
           const float* __restrict__ cosT, const float* __restrict__ sinT)
{
    const int bi = blockIdx.x, bj = blockIdx.y;
    const int tid = threadIdx.x;
    const int lane = tid & 63;
    const int w = tid >> 6;
    const int wm = w >> 1, wn = w & 1;
    const int lg = lane >> 4, lr = lane & 15;

    __shared__ unsigned short As[2][128 * 32];
    __shared__ unsigned short Bs[2][128 * 32];

    f32x4 acc[4][4];
#pragma unroll
    for (int i = 0; i < 4; ++i)
#pragma unroll
        for (int j = 0; j < 4; ++j) acc[i][j] = f32x4{0.f, 0.f, 0.f, 0.f};

    const int srow = lane >> 2;
    const int schk = (lane & 3) ^ ((lane >> 4) & 3);

    auto stage = [&](int k0, int buf) {
#pragma unroll
        for (int q2 = 0; q2 < 2; ++q2) {
            const int seg = w * 2 + q2;                 // 0..7
            const int row = seg * 16 + srow;            // 0..127
            const int loff = seg * 512 + lane * 8;      // shorts (linear dest)
            const size_t ga = (size_t)(bi * 128 + row) * KD + k0 + schk * 8;
            const size_t gb = (size_t)(bj * 128 + row) * KD + k0 + schk * 8;
            gl16(Ah + ga, &As[buf][loff]);
            gl16(Bh + gb, &Bs[buf][loff]);
        }
    };
    const int roff = 8 * (lg ^ ((lr >> 2) & 3));        // read chunk (2-way)
    auto term = [&](const unsigned short* A_, const unsigned short* B_) {
        const unsigned short* Ap = A_ + (wm * 64 + lr) * 32;
        const unsigned short* Bp = B_ + (wn * 64 + lr) * 32;
        f16x8 af[4], bf[4];
#pragma unroll
        for (int i = 0; i < 4; ++i) {
            af[i] = *(const f16x8*)(Ap + i * 512 + roff);
            bf[i] = *(const f16x8*)(Bp + i * 512 + roff);
        }
#pragma unroll
        for (int mi = 0; mi < 4; ++mi)
#pragma unroll
            for (int ni = 0; ni < 4; ++ni)
                acc[mi][ni] = __builtin_amdgcn_mfma_f32_16x16x32_f16(af[mi], bf[ni], acc[mi][ni], 0, 0, 0);
    };

    stage(0, 0);
#pragma unroll 1
    for (int kt = 0; kt < 64; ++kt) {
        const int cur = kt & 1;
        __syncthreads();                      // stage(kt) landed; prev compute done
        if (kt < 63) stage((kt + 1) * 32, cur ^ 1);   // flies during compute
        term(As[cur], Bs[cur]);
    }

    if constexpr (MODE <= 1) {
        unsigned short* OH = (unsigned short*)OutH;
        const float scale = (MODE == 0) ? 0.08838834764831845f : 1.0f;
#pragma unroll
        for (int mi = 0; mi < 4; ++mi) {
            int i0 = bi * 128 + wm * 64 + mi * 16 + lg * 4;  // dout, 4 consecutive
            int h = i0 >> 7, dd = i0 & 127;
            int jp = dd >> 1;
#pragma unroll
            for (int ni = 0; ni < 4; ++ni) {
                int jj = bj * 128 + wn * 64 + ni * 16 + lr;  // token
                int b = jj >> 11, s = jj & 2047;
                float c0 = cosT[s * 64 + jp],     s0 = sinT[s * 64 + jp];
                float c1 = cosT[s * 64 + jp + 1], s1 = sinT[s * 64 + jp + 1];
                f32x4 v = acc[mi][ni];
                float r0 = (v[0] * c0 - v[1] * s0) * scale;
                float r1 = (v[0] * s0 + v[1] * c0) * scale;
                float r2 = (v[2] * c1 - v[3] * s1) * scale;
                float r3 = (v[2] * s1 + v[3] * c1) * scale;
                u16x4 ph = { f2h(r0), f2h(r1), f2h(r2), f2h(r3) };
                *(u16x4*)&OH[((size_t)(b * 16 + h) * 2048 + s) * 128 + dd] = ph;
            }
        }
    } else if constexpr (MODE == 2) {
        unsigned short* O = (unsigned short*)OutH;
#pragma unroll
        for (int mi = 0; mi < 4; ++mi) {
            int i0 = bi * 128 + wm * 64 + mi * 16 + lg * 4;  // token, 4 consecutive
            int b = i0 >> 11, s = i0 & 2047;
#pragma unroll
            for (int ni = 0; ni < 4; ++ni) {
                int jj = bj * 128 + wn * 64 + ni * 16 + lr;  // dout
                int h = jj >> 7, dd = jj & 127;
                f32x4 v = acc[mi][ni];
                u16x4 pk = { f2h(v[0]), f2h(v[1]), f2h(v[2]), f2h(v[3]) };
                *(u16x4*)&O[((size_t)(b * 16 + h) * 128 + dd) * 2048 + s] = pk;
            }
        }
    } else {
        float* O = (float*)OutH;
#pragma unroll
        for (int mi = 0; mi < 4; ++mi) {
            int i0 = bi * 128 + wm * 64 + mi * 16 + lg * 4;  // dout, 4 consecutive
#pragma unroll
            for (int ni = 0; ni < 4; ++ni) {
                int jj = bj * 128 + wn * 64 + ni * 16 + lr;  // token
                *(f32x4*)&O[(size_t)jj * 2048 + i0] = acc[mi][ni];
            }
        }
    }
}

// ---------------- causal flash attention v6 (fp16; structure = r8's attn5) --
// 512 blocks = 64 bh x 8 p; block p does qt=15-p then qt=p -> 68 iters const.
__global__ __launch_bounds__(256)
void attn6(const unsigned short* __restrict__ Qh, const unsigned short* __restrict__ Kh,
           const unsigned short* __restrict__ Vt, unsigned short* __restrict__ Ob)
{
    const int bid = blockIdx.x;
    const int bh = bid & 63;
    const int p  = bid >> 6;                 // 0..7
    const int tid = threadIdx.x;
    const int lane = tid & 63, w = tid >> 6;
    const int lg = lane >> 4, lr = lane & 15;
    const int b = bh >> 4, h = bh & 15;

    __shared__ unsigned short Ks[2][32 * 128];   // 8KB x2, swizzled ^(row&7)
    __shared__ unsigned short Vs[2][128 * 32];   // 8KB x2, swizzled ^((row>>1)&3)
    __shared__ unsigned short Ps[4][16 * 40];    // per-wave P relay, stride 40

    auto stage = [&](int t) {
        const int buf = t & 1;
        const int kv0 = t * 32;
#pragma unroll
        for (int q2 = 0; q2 < 2; ++q2) {
            const int seg = w * 2 + q2;                      // 0..7
            {   // K: 256B rows, chunk ^ (row&7)
                const int row = seg * 4 + (lane >> 4);
                const int gcol = 8 * ((lane & 15) ^ (row & 7));
                gl16(Kh + ((size_t)bh * 2048 + kv0 + row) * 128 + gcol,
                     &Ks[buf][seg * 512 + lane * 8]);
            }
            {   // V: 64B rows, chunk ^ ((row>>1)&3)
                const int row = seg * 16 + (lane >> 2);      // d 0..127
                const int gcol = 8 * ((lane & 3) ^ ((row >> 1) & 3));
                gl16(Vt + ((size_t)bh * 128 + row) * 2048 + kv0 + gcol,
                     &Vs[buf][seg * 512 + lane * 8]);
            }
        }
    };

#pragma unroll 1
    for (int half = 0; half < 2; ++half) {
        const int qt = half ? p : (15 - p);          // 128-row q-tile index
        const int qbase = qt * 128 + w * 32;
        const int qmaxw = qbase + 31;
        const int nkv = 4 * (qt + 1);

        f16x8 qf[2][4];
#pragma unroll
        for (int qg = 0; qg < 2; ++qg) {
            const size_t qoff = ((size_t)bh * 2048 + qbase + qg * 16 + lr) * 128;
#pragma unroll
            for (int kk = 0; kk < 4; ++kk)
                qf[qg][kk] = *(const f16x8*)(Qh + qoff + kk * 32 + lg * 8);
        }

        f32x4 o[8][2];
#pragma unroll
        for (int i = 0; i < 8; ++i)
#pragma unroll
            for (int qg = 0; qg < 2; ++qg) o[i][qg] = f32x4{0.f, 0.f, 0.f, 0.f};
        float m_run[2] = { -1e30f, -1e30f }, l_run[2] = { 0.f, 0.f };

        stage(0);
        __syncthreads();

#pragma unroll 1
        for (int t = 0; t < nkv; ++t) {
            if (t + 1 < nkv) stage(t + 1);       // issue-early into other buffer
            const int buf = t & 1;
            const int kv0 = t * 32;
            if (kv0 <= qmaxw) {
                // QK^T swapped: D[kv][q]; lane: q=lr, kv=m2*16+lg*4+rr
                f32x4 sc[2][2];
#pragma unroll
                for (int m2 = 0; m2 < 2; ++m2)
#pragma unroll
                    for (int qg = 0; qg < 2; ++qg) sc[m2][qg] = f32x4{0.f, 0.f, 0.f, 0.f};
#pragma unroll
                for (int m2 = 0; m2 < 2; ++m2)
#pragma unroll
                    for (int kk = 0; kk < 4; ++kk) {
                        const int go = 8 * ((4 * kk + lg) ^ (lr & 7));
                        f16x8 kf = *(const f16x8*)&Ks[buf][(m2 * 16 + lr) * 128 + go];
#pragma unroll
                        for (int qg = 0; qg < 2; ++qg)
                            sc[m2][qg] = __builtin_amdgcn_mfma_f32_16x16x32_f16(kf, qf[qg][kk], sc[m2][qg], 0, 0, 0);
                    }
#pragma unroll
                for (int qg = 0; qg < 2; ++qg) {
                    const int q = qbase + qg * 16 + lr;
                    float pmax = -1e30f;
#pragma unroll
                    for (int m2 = 0; m2 < 2; ++m2)
#pragma unroll
                        for (int rr = 0; rr < 4; ++rr) {
                            int kvg = kv0 + m2 * 16 + lg * 4 + rr;
                            float sv = (kvg <= q) ? sc[m2][qg][rr] : -1e30f;
                            sc[m2][qg][rr] = sv;
                            pmax = fmaxf(pmax, sv);
                        }
                    pmax = fmaxf(pmax, __shfl_xor(pmax, 16));
                    pmax = fmaxf(pmax, __shfl_xor(pmax, 32));
                    // T13 defer-max: skip rescale unless max grew past THR=8
                    if (!__all(pmax <= m_run[qg] + 8.0f)) {
                        float mnew = fmaxf(m_run[qg], pmax);
                        float alpha = __expf(m_run[qg] - mnew);
                        m_run[qg] = mnew;
                        l_run[qg] *= alpha;
#pragma unroll
                        for (int ni = 0; ni < 8; ++ni) {
                            o[ni][qg][0] *= alpha; o[ni][qg][1] *= alpha;
                            o[ni][qg][2] *= alpha; o[ni][qg][3] *= alpha;
                        }
                    }
                    float psum = 0.f;
                    u16x4 pq[2];
#pragma unroll
                    for (int m2 = 0; m2 < 2; ++m2)
#pragma unroll
                        for (int rr = 0; rr < 4; ++rr) {
                            float pv = __expf(sc[m2][qg][rr] - m_run[qg]);
                            unsigned short ph = f2h(pv);
                            pq[m2][rr] = ph;
                            psum += h2f(ph);     // consistent with PV numerator
                        }
                    l_run[qg] += psum;
                    // P relay: C-layout -> B-frag via per-wave LDS (stride 40)
                    *(u16x4*)&Ps[w][lr * 40 + lg * 4]      = pq[0];
                    *(u16x4*)&Ps[w][lr * 40 + 16 + lg * 4] = pq[1];
                    f16x8 pf = *(const f16x8*)&Ps[w][lr * 40 + lg * 8];
                    // PV swapped: O^T[d][q], A = Vt rows (d), B = P (K=32)
#pragma unroll
                    for (int ni = 0; ni < 8; ++ni) {
                        f16x8 vf = *(const f16x8*)&Vs[buf][(ni * 16 + lr) * 32 + 8 * (lg ^ ((lr >> 1) & 3))];
                        o[ni][qg] = __builtin_amdgcn_mfma_f32_16x16x32_f16(vf, pf, o[ni][qg], 0, 0, 0);
                    }
                }
            }
            __syncthreads();
        }

#pragma unroll
        for (int qg = 0; qg < 2; ++qg) {
            float l = l_run[qg];
            l += __shfl_xor(l, 16);
            l += __shfl_xor(l, 32);
            float inv = 1.f / l;
            const int q = qbase + qg * 16 + lr;
            unsigned short* Op = Ob + (((size_t)(b * 2048 + q) * 16 + h) * 128);
#pragma unroll
            for (int ni = 0; ni < 8; ++ni) {
                u16x4 pk = { f2h(o[ni][qg][0] * inv), f2h(o[ni][qg][1] * inv),
                             f2h(o[ni][qg][2] * inv), f2h(o[ni][qg][3] * inv) };
                *(u16x4*)&Op[ni * 16 + lg * 4] = pk;
            }
        }
    }
}

extern "C" void kernel_launch(void* const* d_in, const int* in_sizes, int n_in,
                              void* d_out, int out_size, void* d_ws, size_t ws_size,
                              hipStream_t stream) {
    const float* x  = (const float*)d_in[0];
    const float* Wq = (const float*)d_in[1];
    const float* Wk = (const float*)d_in[2];
    const float* Wv = (const float*)d_in[3];
    const float* Wo = (const float*)d_in[4];

    char* ws = (char*)d_ws;
    float* cosT = (float*)ws;                                   // 512 KB
    float* sinT = cosT + 2048 * 64;                             // 512 KB
    unsigned short* xh  = (unsigned short*)(ws + (1 << 20));    // 33.5 MB
    unsigned short* Vt  = xh  + (size_t)16777216;               // 33.5 MB
    unsigned short* Wqh = Vt  + (size_t)16777216;               // 8.4 MB
    unsigned short* Wkh = Wqh + (size_t)4194304;                // 8.4 MB
    unsigned short* Wvh = Wkh + (size_t)4194304;                // 8.4 MB
    unsigned short* Woh = Wvh + (size_t)4194304;                // 8.4 MB (ws ~102 MB)

    // attn_b aliases xh (x dead after V GEMM)
    unsigned short* attn_b = xh;

    // d_out (67 MB fp32) hosts Qh/Kh until the final GEMM overwrites it
    unsigned short* Qh = (unsigned short*)d_out;
    unsigned short* Kh = Qh + (size_t)16777216;

    rope_tables<<<dim3(512), 256, 0, stream>>>(cosT, sinT);
    precvt<<<dim3(16384), 256, 0, stream>>>(x, xh, 4194304);
    precvtW<<<dim3(4096, 4), 256, 0, stream>>>(Wq, Wk, Wv, Wo, Wqh, Wkh, Wvh, Woh);

    gemm4<0><<<dim3(16, 64), 256, 0, stream>>>(Wqh, xh, Qh, cosT, sinT);
    gemm4<1><<<dim3(16, 64), 256, 0, stream>>>(Wkh, xh, Kh, cosT, sinT);
    gemm4<2><<<dim3(64, 16), 256, 0, stream>>>(xh, Wvh, Vt, cosT, sinT);
    attn6<<<dim3(512), 256, 0, stream>>>(Qh, Kh, Vt, attn_b);
    gemm4<3><<<dim3(16, 64), 256, 0, stream>>>(Woh, attn_b, d_out, cosT, sinT);
}